// Round 9
// baseline (844.746 us; speedup 1.0000x reference)
//
#include <hip/hip_runtime.h>
#include <stdint.h>

typedef unsigned short u16;
typedef __attribute__((ext_vector_type(8))) short s16x8;   // 8 bf16 = 4 VGPR
typedef __attribute__((ext_vector_type(4))) short s16x4;
typedef __attribute__((ext_vector_type(4))) float f32x4;

#define DEV static __device__ __forceinline__

DEV u16 f2bf(float f) {
  union { float f; unsigned u; } v; v.f = f;
  unsigned u = v.u;
  u += 0x7fffu + ((u >> 16) & 1u);   // RNE
  return (u16)(u >> 16);
}
DEV float bf2f(u16 h) {
  union { unsigned u; float f; } v; v.u = ((unsigned)h) << 16;
  return v.f;
}

#define GL2LDS(gp, lp) __builtin_amdgcn_global_load_lds( \
    (const __attribute__((address_space(1))) unsigned int*)(const void*)(gp), \
    (__attribute__((address_space(3))) unsigned int*)(void*)(lp), 16, 0, 0)

// dims: B=2 T=2048 DM=1024 H=4 DK=256 DV=512; BT=4096
// Precision scheme: every GEMM runs 3-term split-bf16 (hi/lo), i.e. near-fp32.
// Only single-bf16 points: o_n (normalized o) and gate = silu(g)*gw.

// ---------------- split ALL inputs into bf16 hi/lo ----------------
__global__ __launch_bounds__(256) void cvt_split_k(
    const float* __restrict__ x,  const float* __restrict__ wq,
    const float* __restrict__ wk, const float* __restrict__ wv,
    const float* __restrict__ wg, const float* __restrict__ wo,
    u16* __restrict__ xh,  u16* __restrict__ xl,
    u16* __restrict__ wqh, u16* __restrict__ wql,
    u16* __restrict__ wkh, u16* __restrict__ wkl,
    u16* __restrict__ wvh, u16* __restrict__ wvl,
    u16* __restrict__ wgh, u16* __restrict__ wgl,
    u16* __restrict__ woh, u16* __restrict__ wol)
{
  long e = ((long)blockIdx.x * 256 + threadIdx.x) * 8;
  const float* src; u16 *dh, *dl;
  if (e < 4194304L)                    { src = x;  dh = xh;  dl = xl;  }
  else if ((e -= 4194304L) < 1048576L) { src = wq; dh = wqh; dl = wql; }
  else if ((e -= 1048576L) < 1048576L) { src = wk; dh = wkh; dl = wkl; }
  else if ((e -= 1048576L) < 2097152L) { src = wv; dh = wvh; dl = wvl; }
  else if ((e -= 2097152L) < 2097152L) { src = wg; dh = wgh; dl = wgl; }
  else                  { e -= 2097152L; src = wo; dh = woh; dl = wol; }
  f32x4 a = *(const f32x4*)(src + e);
  f32x4 b = *(const f32x4*)(src + e + 4);
  float f[8] = {a[0], a[1], a[2], a[3], b[0], b[1], b[2], b[3]};
  s16x8 rh, rl;
#pragma unroll
  for (int j = 0; j < 8; ++j) {
    u16 hi = f2bf(f[j]);
    rh[j] = (short)hi;
    rl[j] = (short)f2bf(f[j] - bf2f(hi));
  }
  *(s16x8*)(dh + e) = rh;
  *(s16x8*)(dl + e) = rl;
}

// ---------------- RoPE table: cos/sin [T=2048][128] ----------------
__global__ __launch_bounds__(256) void rope_table_k(float* __restrict__ ct, float* __restrict__ st)
{
  int i = blockIdx.x * 256 + threadIdx.x;     // 262144
  int t = i >> 7, j = i & 127;
  float freq = powf(10000.0f, -(float)j * (1.0f / 128.0f));
  float a = (float)t * freq;
  ct[i] = cosf(a);
  st[i] = sinf(a);
}

// ---------------- 3-term split GEMM core: C=(Ah+Al)(Bh+Bl), 128x128xBK32 -----
DEV void gemm3_core(const u16* __restrict__ Ah, const u16* __restrict__ Al,
                    const u16* __restrict__ Bh, const u16* __restrict__ Bl,
                    int K, int m0, u16* LAh, u16* LAl, u16* LBh, u16* LBl,
                    f32x4 acc[4][4], int tid)
{
  const int lane = tid & 63, wave = tid >> 6;
  const int wr = wave >> 1, wc = wave & 1;
  const int l15 = lane & 15, l4 = lane >> 4;
  const int nsteps = K >> 5;
  for (int kt = 0; kt < nsteps; ++kt) {
    const int kb = kt << 5;
#pragma unroll
    for (int c = 0; c < 2; ++c) {
      int chunk = c * 256 + tid;
      int row = chunk >> 2, kc = (chunk & 3) << 3;
      size_t aoff = (size_t)(m0 + row) * K + kb + kc;
      size_t boff = (size_t)row * K + kb + kc;
      char* ldst = (char*)0 + c * 4096 + wave * 1024;
      GL2LDS(Ah + aoff, (char*)LAh + (size_t)ldst);
      GL2LDS(Al + aoff, (char*)LAl + (size_t)ldst);
      GL2LDS(Bh + boff, (char*)LBh + (size_t)ldst);
      GL2LDS(Bl + boff, (char*)LBl + (size_t)ldst);
    }
    __syncthreads();
    s16x8 ah[4], al[4], bh[4], bl[4];
#pragma unroll
    for (int i = 0; i < 4; ++i) {
      int ar = (wr * 64 + i * 16 + l15) * 32 + l4 * 8;
      int br = (wc * 64 + i * 16 + l15) * 32 + l4 * 8;
      ah[i] = *(const s16x8*)&LAh[ar];
      al[i] = *(const s16x8*)&LAl[ar];
      bh[i] = *(const s16x8*)&LBh[br];
      bl[i] = *(const s16x8*)&LBl[br];
    }
#pragma unroll
    for (int i = 0; i < 4; ++i)
#pragma unroll
      for (int j = 0; j < 4; ++j) {
        acc[i][j] = __builtin_amdgcn_mfma_f32_16x16x32_bf16(ah[i], bh[j], acc[i][j], 0, 0, 0);
        acc[i][j] = __builtin_amdgcn_mfma_f32_16x16x32_bf16(ah[i], bl[j], acc[i][j], 0, 0, 0);
        acc[i][j] = __builtin_amdgcn_mfma_f32_16x16x32_bf16(al[i], bh[j], acc[i][j], 0, 0, 0);
      }
    __syncthreads();
  }
}

// ---------------- GEMM(q,k,v): x @ W^T, near-fp32; q,k fp32 out; v split -----
__global__ __launch_bounds__(256, 2) void gemm_qkv_k(
    const u16* __restrict__ xh, const u16* __restrict__ xl,
    const u16* __restrict__ wqh, const u16* __restrict__ wql,
    const u16* __restrict__ wkh, const u16* __restrict__ wkl,
    const u16* __restrict__ wvh, const u16* __restrict__ wvl,
    float* __restrict__ Qf, float* __restrict__ Kf,
    u16* __restrict__ vth, u16* __restrict__ vtl)
{
  __shared__ u16 LAh[4096], LAl[4096], LBh[4096], LBl[4096];
  const int m0 = blockIdx.x * 128;
  const int nt = blockIdx.y;
  const u16 *Bh, *Bl; int seg, nl0;
  if (nt < 8)       { Bh = wqh + (size_t)nt * 131072;        Bl = wql + (size_t)nt * 131072;        seg = 0; nl0 = nt * 128; }
  else if (nt < 16) { Bh = wkh + (size_t)(nt - 8) * 131072;  Bl = wkl + (size_t)(nt - 8) * 131072;  seg = 1; nl0 = (nt - 8) * 128; }
  else              { Bh = wvh + (size_t)(nt - 16) * 131072; Bl = wvl + (size_t)(nt - 16) * 131072; seg = 2; nl0 = (nt - 16) * 128; }

  f32x4 acc[4][4];
#pragma unroll
  for (int i = 0; i < 4; ++i)
#pragma unroll
    for (int j = 0; j < 4; ++j) acc[i][j] = (f32x4){0.f, 0.f, 0.f, 0.f};

  const int tid = threadIdx.x;
  gemm3_core(xh, xl, Bh, Bl, 1024, m0, LAh, LAl, LBh, LBl, acc, tid);

  const int lane = tid & 63, wave = tid >> 6;
  const int wr = wave >> 1, wc = wave & 1;
  const int l15 = lane & 15, l4 = lane >> 4;
#pragma unroll
  for (int i = 0; i < 4; ++i) {
    int rowb = m0 + wr * 64 + i * 16 + l4 * 4;
    int b_ = rowb >> 11, trow = rowb & 2047;
#pragma unroll
    for (int j = 0; j < 4; ++j) {
      int col = nl0 + wc * 64 + j * 16 + l15;
      f32x4 v = acc[i][j];
      if (seg <= 1) {          // q/k -> fp32 (b,h,t,d)
        int h_ = col >> 8, d_ = col & 255;
        float* dst = (seg == 0 ? Qf : Kf) + ((size_t)((b_ * 4 + h_) * 2048 + trow)) * 256 + d_;
#pragma unroll
        for (int r = 0; r < 4; ++r) dst[(size_t)r * 256] = v[r];
      } else {                 // v -> (b,h,d,t) split hi/lo bf16
        int h_ = col >> 9, d_ = col & 511;
        size_t base = ((size_t)((b_ * 4 + h_) * 512 + d_)) * 2048 + trow;
        s16x4 hv, lv;
#pragma unroll
        for (int r = 0; r < 4; ++r) {
          u16 hi = f2bf(v[r]);
          hv[r] = (short)hi;
          lv[r] = (short)f2bf(v[r] - bf2f(hi));
        }
        *(s16x4*)(vth + base) = hv;
        *(s16x4*)(vtl + base) = lv;
      }
    }
  }
}

// ---------------- GEMM(gate): silu(x @ Wg^T)*gw -> bf16 (bt, hdv) ------------
__global__ __launch_bounds__(256, 2) void gemm_gate_k(
    const u16* __restrict__ xh, const u16* __restrict__ xl,
    const u16* __restrict__ wgh, const u16* __restrict__ wgl,
    const float* __restrict__ gw, u16* __restrict__ gateb)
{
  __shared__ u16 LAh[4096], LAl[4096], LBh[4096], LBl[4096];
  const int m0 = blockIdx.x * 128;
  const int nl0 = blockIdx.y * 128;
  f32x4 acc[4][4];
#pragma unroll
  for (int i = 0; i < 4; ++i)
#pragma unroll
    for (int j = 0; j < 4; ++j) acc[i][j] = (f32x4){0.f, 0.f, 0.f, 0.f};
  const int tid = threadIdx.x;
  gemm3_core(xh, xl, wgh + (size_t)blockIdx.y * 131072, wgl + (size_t)blockIdx.y * 131072,
             1024, m0, LAh, LAl, LBh, LBl, acc, tid);
  const int lane = tid & 63, wave = tid >> 6;
  const int wr = wave >> 1, wc = wave & 1;
  const int l15 = lane & 15, l4 = lane >> 4;
#pragma unroll
  for (int i = 0; i < 4; ++i) {
    int rowb = m0 + wr * 64 + i * 16 + l4 * 4;
#pragma unroll
    for (int j = 0; j < 4; ++j) {
      int col = nl0 + wc * 64 + j * 16 + l15;
      float gwv = gw[col & 511];
#pragma unroll
      for (int r = 0; r < 4; ++r) {
        float g = acc[i][j][r];
        float gate = g / (1.0f + expf(-g)) * gwv;
        gateb[(size_t)(rowb + r) * 2048 + col] = f2bf(gate);
      }
    }
  }
}

// ---------------- RoPE fp32 -> in-place split bf16 [hi 256 | lo 256] ---------
// one wave per row; q rows scaled by dk^-0.5
__global__ __launch_bounds__(256) void rope_split_k(
    float* __restrict__ Qf, float* __restrict__ Kf,
    const float* __restrict__ ct, const float* __restrict__ st)
{
  int row = blockIdx.x * 4 + (threadIdx.x >> 6);   // 0..32767
  int lane = threadIdx.x & 63;
  float* base; float scale; int r = row;
  if (r < 16384) { base = Qf; scale = 0.0625f; }
  else { r -= 16384; base = Kf; scale = 1.0f; }
  int t = r & 2047;
  float* p = base + (size_t)r * 256;
  f32x4 v = *(const f32x4*)(p + lane * 4);
  int j0 = (lane & 31) * 4;
  f32x4 c = *(const f32x4*)(ct + t * 128 + j0);
  f32x4 s = *(const f32x4*)(st + t * 128 + j0);
  f32x4 sw, o;
#pragma unroll
  for (int q = 0; q < 4; ++q) sw[q] = __shfl_xor(v[q], 32);
#pragma unroll
  for (int q = 0; q < 4; ++q)
    o[q] = (lane < 32 ? v[q] * c[q] - sw[q] * s[q]
                      : sw[q] * s[q] + v[q] * c[q]) * scale;
  s16x4 hi4, lo4;
#pragma unroll
  for (int q = 0; q < 4; ++q) {
    u16 hi = f2bf(o[q]);
    hi4[q] = (short)hi;
    lo4[q] = (short)f2bf(o[q] - bf2f(hi));
  }
  u16* ub = (u16*)p;
  int dd = j0 + ((lane >> 5) << 7);
  *(s16x4*)(ub + dd) = hi4;          // hi plane [0,256)
  *(s16x4*)(ub + 256 + dd) = lo4;    // lo plane [256,512)
}

// ---------------- Retention + fused RMS-norm -> o_n bf16 ---------------------
// QBLK=64, 4 waves: wave = t-frag owner (QK^T) AND d-range owner (PV).
// bh = bid&7 -> XCD affinity (per-XCD L2 keeps one (b,h) K/V working set).
// 3-term QK^T and PV; K,V read L2-direct; P hi/lo via LDS.
__global__ __launch_bounds__(256) void retention_k(
    const u16* __restrict__ QS, const u16* __restrict__ KS,
    const u16* __restrict__ VTH, const u16* __restrict__ VTL,
    u16* __restrict__ ON)
{
  __shared__ u16 Pldsh[64 * 32];   // 4KB, rows t, cols s, XOR-swizzled
  __shared__ u16 Pldsl[64 * 32];   // 4KB
  __shared__ float wpart[4][64];
  __shared__ float rmsl[64];

  const int bid = blockIdx.x;
  const int bh = bid & 7;          // round-robin dispatch -> same XCD per bh
  const int qt = bid >> 3;         // 0..31 (64-row q tile)
  const int t0 = qt * 64;
  const int h = bh & 3;
  const float ld = log1pf(-exp2f(-5.0f - (float)h));
  const float c2 = ld * 1.44269504f;

  const int tid = threadIdx.x;
  const int lane = tid & 63, wave = tid >> 6;
  const int l15 = lane & 15, l4 = lane >> 4;

  // Q fragments (hi/lo) for this wave's t-frag (tf = wave)
  s16x8 qfh[8], qfl[8];
  {
    const u16* qrow = QS + (size_t)(bh * 2048 + t0 + wave * 16 + l15) * 512 + l4 * 8;
#pragma unroll
    for (int kf = 0; kf < 8; ++kf) {
      qfh[kf] = *(const s16x8*)(qrow + kf * 32);
      qfl[kf] = *(const s16x8*)(qrow + kf * 32 + 256);
    }
  }

  const u16* kbase = KS + (size_t)(bh * 2048) * 512;
  const u16* vbh = VTH + (size_t)(bh * 512 + wave * 128) * 2048;
  const u16* vbl = VTL + (size_t)(bh * 512 + wave * 128) * 2048;

  f32x4 oacc[4][8];   // [mf: 4 t-frags][nf: 8 d-frags of this wave's 128 d]
#pragma unroll
  for (int i = 0; i < 4; ++i)
#pragma unroll
    for (int j = 0; j < 8; ++j) oacc[i][j] = (f32x4){0.f, 0.f, 0.f, 0.f};

  const int nkt = 2 * qt + 2;      // k-tiles of 32 covering s <= t0+63
  for (int kt = 0; kt < nkt; ++kt) {
    const int s0 = kt * 32;
    // S^T for this wave's t-frag: two sf 16x16 tiles, 3-term split
    f32x4 sacc[2];
#pragma unroll
    for (int sf = 0; sf < 2; ++sf) {
      sacc[sf] = (f32x4){0.f, 0.f, 0.f, 0.f};
      const u16* krow = kbase + (size_t)(s0 + sf * 16 + l15) * 512 + l4 * 8;
#pragma unroll
      for (int kf = 0; kf < 8; ++kf) {
        s16x8 kh = *(const s16x8*)(krow + kf * 32);
        s16x8 kl = *(const s16x8*)(krow + kf * 32 + 256);
        sacc[sf] = __builtin_amdgcn_mfma_f32_16x16x32_bf16(kh, qfh[kf], sacc[sf], 0, 0, 0);
        sacc[sf] = __builtin_amdgcn_mfma_f32_16x16x32_bf16(kh, qfl[kf], sacc[sf], 0, 0, 0);
        sacc[sf] = __builtin_amdgcn_mfma_f32_16x16x32_bf16(kl, qfh[kf], sacc[sf], 0, 0, 0);
      }
    }
    // decay + split P; write to LDS [t][s]
    const int tl = wave * 16 + l15;     // local t row 0..63
    const int tg = t0 + tl;
    __syncthreads();   // prior iteration's P reads done
#pragma unroll
    for (int sf = 0; sf < 2; ++sf) {
      s16x4 pvh, pvl;
#pragma unroll
      for (int r = 0; r < 4; ++r) {
        int sl = sf * 16 + l4 * 4 + r;
        int diff = tg - (s0 + sl);
        float f = (diff >= 0) ? sacc[sf][r] * exp2f(c2 * (float)diff) : 0.0f;
        u16 hi = f2bf(f);
        pvh[r] = (short)hi;
        pvl[r] = (short)f2bf(f - bf2f(hi));
      }
      int pboff = ((tl * 64 + (sf * 16 + l4 * 4) * 2) ^ ((tl & 7) << 4));
      *(s16x4*)((char*)Pldsh + pboff) = pvh;
      *(s16x4*)((char*)Pldsl + pboff) = pvl;
    }
    __syncthreads();
    // PV: O[t][d] += P[t][s] * Vt[d][s], 3-term; wave owns d in [wave*128,+128)
    s16x8 pah[4], pal[4];
#pragma unroll
    for (int mf = 0; mf < 4; ++mf) {
      int prow = mf * 16 + l15;
      int poff = ((prow * 64 + l4 * 16) ^ ((prow & 7) << 4));
      pah[mf] = *(const s16x8*)((char*)Pldsh + poff);
      pal[mf] = *(const s16x8*)((char*)Pldsl + poff);
    }
#pragma unroll
    for (int nf = 0; nf < 8; ++nf) {
      size_t voff = (size_t)(nf * 16 + l15) * 2048 + s0 + l4 * 8;
      s16x8 vh = *(const s16x8*)(vbh + voff);
      s16x8 vl = *(const s16x8*)(vbl + voff);
#pragma unroll
      for (int mf = 0; mf < 4; ++mf) {
        oacc[mf][nf] = __builtin_amdgcn_mfma_f32_16x16x32_bf16(pah[mf], vh, oacc[mf][nf], 0, 0, 0);
        oacc[mf][nf] = __builtin_amdgcn_mfma_f32_16x16x32_bf16(pah[mf], vl, oacc[mf][nf], 0, 0, 0);
        oacc[mf][nf] = __builtin_amdgcn_mfma_f32_16x16x32_bf16(pal[mf], vh, oacc[mf][nf], 0, 0, 0);
      }
    }
  }
  // fused RMS over dv=512 per t-row (64 rows), then o_n -> bf16
  float ss[4][4];
#pragma unroll
  for (int mf = 0; mf < 4; ++mf)
#pragma unroll
    for (int r = 0; r < 4; ++r) {
      float a = 0.f;
#pragma unroll
      for (int nf = 0; nf < 8; ++nf) { float o = oacc[mf][nf][r]; a += o * o; }
      ss[mf][r] = a;
    }
#pragma unroll
  for (int m = 1; m < 16; m <<= 1)
#pragma unroll
    for (int mf = 0; mf < 4; ++mf)
#pragma unroll
      for (int r = 0; r < 4; ++r) ss[mf][r] += __shfl_xor(ss[mf][r], m);
  if (l15 == 0) {
#pragma unroll
    for (int mf = 0; mf < 4; ++mf)
#pragma unroll
      for (int r = 0; r < 4; ++r) wpart[wave][mf * 16 + l4 * 4 + r] = ss[mf][r];
  }
  __syncthreads();
  if (tid < 64)
    rmsl[tid] = rsqrtf((wpart[0][tid] + wpart[1][tid] + wpart[2][tid] + wpart[3][tid])
                       * (1.0f / 512.0f) + 1e-5f);
  __syncthreads();
  u16* ob = ON + (size_t)(bh * 2048 + t0) * 512;
#pragma unroll
  for (int mf = 0; mf < 4; ++mf)
#pragma unroll
    for (int r = 0; r < 4; ++r) {
      int trow = mf * 16 + l4 * 4 + r;
      float rr = rmsl[trow];
#pragma unroll
      for (int nf = 0; nf < 8; ++nf)
        ob[(size_t)trow * 512 + wave * 128 + nf * 16 + l15] = f2bf(oacc[mf][nf][r] * rr);
    }
}

// ---------------- og = o_n * gate -> split hi/lo (bt, hdv) layout ------------
__global__ __launch_bounds__(256) void og_k(
    const u16* __restrict__ ON, const u16* __restrict__ gateb,
    u16* __restrict__ ogh, u16* __restrict__ ogl)
{
  size_t i = ((size_t)blockIdx.x * 256 + threadIdx.x) * 8;
  int d = (int)(i & 511);
  int t = (int)((i >> 9) & 2047);
  int bh = (int)(i >> 20);
  int h = bh & 3, b = bh >> 2;
  size_t gidx = ((size_t)(b * 2048 + t)) * 2048 + h * 512 + d;
  s16x8 o8 = *(const s16x8*)(ON + i);
  s16x8 g8 = *(const s16x8*)(gateb + gidx);
  s16x8 rh, rl;
#pragma unroll
  for (int j = 0; j < 8; ++j) {
    float p = bf2f((u16)o8[j]) * bf2f((u16)g8[j]);
    u16 hi = f2bf(p);
    rh[j] = (short)hi;
    rl[j] = (short)f2bf(p - bf2f(hi));
  }
  *(s16x8*)(ogh + gidx) = rh;
  *(s16x8*)(ogl + gidx) = rl;
}

// ---------------- GEMM2: (og_h+og_l) @ (Wo_h+Wo_l)^T -> out fp32 -------------
__global__ __launch_bounds__(256, 2) void gemm_out_k(
    const u16* __restrict__ OGh, const u16* __restrict__ OGl,
    const u16* __restrict__ WOh, const u16* __restrict__ WOl,
    float* __restrict__ OUT)
{
  __shared__ u16 LAh[4096], LAl[4096], LBh[4096], LBl[4096];
  const int m0 = blockIdx.x * 128;
  const int n0 = blockIdx.y * 128;
  f32x4 acc[4][4];
#pragma unroll
  for (int i = 0; i < 4; ++i)
#pragma unroll
    for (int j = 0; j < 4; ++j) acc[i][j] = (f32x4){0.f, 0.f, 0.f, 0.f};
  const int tid = threadIdx.x;
  gemm3_core(OGh, OGl, WOh + (size_t)n0 * 2048, WOl + (size_t)n0 * 2048,
             2048, m0, LAh, LAl, LBh, LBl, acc, tid);
  const int lane = tid & 63, wave = tid >> 6;
  const int wr = wave >> 1, wc = wave & 1;
  const int l15 = lane & 15, l4 = lane >> 4;
#pragma unroll
  for (int i = 0; i < 4; ++i) {
    int rowb = m0 + wr * 64 + i * 16 + l4 * 4;
#pragma unroll
    for (int j = 0; j < 4; ++j) {
      int col = n0 + wc * 64 + j * 16 + l15;
#pragma unroll
      for (int r = 0; r < 4; ++r)
        OUT[(size_t)(rowb + r) * 1024 + col] = acc[i][j][r];
    }
  }
}

// ---------------- launch ----------------
extern "C" void kernel_launch(void* const* d_in, const int* in_sizes, int n_in,
                              void* d_out, int out_size, void* d_ws, size_t ws_size,
                              hipStream_t stream)
{
  (void)in_sizes; (void)n_in; (void)out_size; (void)ws_size;
  const float* x  = (const float*)d_in[0];
  const float* wq = (const float*)d_in[1];
  const float* wk = (const float*)d_in[2];
  const float* wv = (const float*)d_in[3];
  const float* wg = (const float*)d_in[4];
  const float* wo = (const float*)d_in[5];
  const float* gw = (const float*)d_in[6];
  char* ws = (char*)d_ws;
#define MB(x) ((size_t)(x) * 1048576)
  // persistent regions (peak 112 MB)
  u16* xh  = (u16*)(ws + MB(0));    // dies after gemm_gate
  u16* xl  = (u16*)(ws + MB(8));
  u16* wqh = (u16*)(ws + MB(16));   // wq/wk/wv die after gemm_qkv
  u16* wql = (u16*)(ws + MB(18));
  u16* wkh = (u16*)(ws + MB(20));
  u16* wkl = (u16*)(ws + MB(22));
  u16* wvh = (u16*)(ws + MB(24));
  u16* wvl = (u16*)(ws + MB(28));
  u16* wgh = (u16*)(ws + MB(32));   // dies after gemm_gate
  u16* wgl = (u16*)(ws + MB(36));
  u16* woh = (u16*)(ws + MB(40));   // to end
  u16* wol = (u16*)(ws + MB(44));
  float* Qf = (float*)(ws + MB(48)); // fp32 -> split-in-place; dies after retention
  float* Kf = (float*)(ws + MB(64));
  u16* vth = (u16*)(ws + MB(80));   // dies after retention
  u16* vtl = (u16*)(ws + MB(96));
  // aliases over dead regions
  u16* gateb = (u16*)(ws + MB(16)); // over wq/wk/wv after gemm_qkv; dies after og_k
  float* ct  = (float*)(ws + MB(32)); // over wgh after gemm_gate; dies after rope
  float* st  = (float*)(ws + MB(33));
  u16* onb   = (u16*)(ws + MB(0));  // o_n over x after gemm_gate; dies after og_k
  u16* ogh   = (u16*)(ws + MB(48)); // over Qf/Kf after retention; to gemm_out
  u16* ogl   = (u16*)(ws + MB(64));
  u16* qs = (u16*)(ws + MB(48));    // split q/k views (in-place over Qf/Kf)
  u16* ks = (u16*)(ws + MB(64));
  float* out = (float*)d_out;

  cvt_split_k<<<6144, 256, 0, stream>>>(x, wq, wk, wv, wg, wo,
      xh, xl, wqh, wql, wkh, wkl, wvh, wvl, wgh, wgl, woh, wol);
  gemm_qkv_k<<<dim3(32, 32), 256, 0, stream>>>(xh, xl, wqh, wql, wkh, wkl, wvh, wvl,
      Qf, Kf, vth, vtl);
  gemm_gate_k<<<dim3(32, 16), 256, 0, stream>>>(xh, xl, wgh, wgl, gw, gateb);
  rope_table_k<<<1024, 256, 0, stream>>>(ct, st);
  rope_split_k<<<8192, 256, 0, stream>>>(Qf, Kf, ct, st);
  retention_k<<<256, 256, 0, stream>>>(qs, ks, vth, vtl, onb);
  og_k<<<4096, 256, 0, stream>>>(onb, gateb, ogh, ogl);
  gemm_out_k<<<dim3(32, 8), 256, 0, stream>>>(ogh, ogl, woh, wol, out);
#undef MB
}

// Round 10
// 663.343 us; speedup vs baseline: 1.2735x; 1.2735x over previous
//
#include <hip/hip_runtime.h>
#include <stdint.h>

typedef unsigned short u16;
typedef __attribute__((ext_vector_type(8))) short s16x8;   // 8 bf16 = 4 VGPR
typedef __attribute__((ext_vector_type(4))) short s16x4;
typedef __attribute__((ext_vector_type(4))) float f32x4;

#define DEV static __device__ __forceinline__

DEV u16 f2bf(float f) {
  union { float f; unsigned u; } v; v.f = f;
  unsigned u = v.u;
  u += 0x7fffu + ((u >> 16) & 1u);   // RNE
  return (u16)(u >> 16);
}
DEV float bf2f(u16 h) {
  union { unsigned u; float f; } v; v.u = ((unsigned)h) << 16;
  return v.f;
}

#define GL2LDS(gp, lp) __builtin_amdgcn_global_load_lds( \
    (const __attribute__((address_space(1))) unsigned int*)(const void*)(gp), \
    (__attribute__((address_space(3))) unsigned int*)(void*)(lp), 16, 0, 0)

// dims: B=2 T=2048 DM=1024 H=4 DK=256 DV=512; BT=4096
// Precision scheme: every GEMM runs 3-term split-bf16 (hi/lo), i.e. near-fp32.
// Only single-bf16 points: o_n (normalized o) and gate = silu(g)*gw.

// ---------------- split ALL inputs into bf16 hi/lo ----------------
__global__ __launch_bounds__(256) void cvt_split_k(
    const float* __restrict__ x,  const float* __restrict__ wq,
    const float* __restrict__ wk, const float* __restrict__ wv,
    const float* __restrict__ wg, const float* __restrict__ wo,
    u16* __restrict__ xh,  u16* __restrict__ xl,
    u16* __restrict__ wqh, u16* __restrict__ wql,
    u16* __restrict__ wkh, u16* __restrict__ wkl,
    u16* __restrict__ wvh, u16* __restrict__ wvl,
    u16* __restrict__ wgh, u16* __restrict__ wgl,
    u16* __restrict__ woh, u16* __restrict__ wol)
{
  long e = ((long)blockIdx.x * 256 + threadIdx.x) * 8;
  const float* src; u16 *dh, *dl;
  if (e < 4194304L)                    { src = x;  dh = xh;  dl = xl;  }
  else if ((e -= 4194304L) < 1048576L) { src = wq; dh = wqh; dl = wql; }
  else if ((e -= 1048576L) < 1048576L) { src = wk; dh = wkh; dl = wkl; }
  else if ((e -= 1048576L) < 2097152L) { src = wv; dh = wvh; dl = wvl; }
  else if ((e -= 2097152L) < 2097152L) { src = wg; dh = wgh; dl = wgl; }
  else                  { e -= 2097152L; src = wo; dh = woh; dl = wol; }
  f32x4 a = *(const f32x4*)(src + e);
  f32x4 b = *(const f32x4*)(src + e + 4);
  float f[8] = {a[0], a[1], a[2], a[3], b[0], b[1], b[2], b[3]};
  s16x8 rh, rl;
#pragma unroll
  for (int j = 0; j < 8; ++j) {
    u16 hi = f2bf(f[j]);
    rh[j] = (short)hi;
    rl[j] = (short)f2bf(f[j] - bf2f(hi));
  }
  *(s16x8*)(dh + e) = rh;
  *(s16x8*)(dl + e) = rl;
}

// ---------------- RoPE table: cos/sin [T=2048][128] ----------------
__global__ __launch_bounds__(256) void rope_table_k(float* __restrict__ ct, float* __restrict__ st)
{
  int i = blockIdx.x * 256 + threadIdx.x;     // 262144
  int t = i >> 7, j = i & 127;
  float freq = powf(10000.0f, -(float)j * (1.0f / 128.0f));
  float a = (float)t * freq;
  ct[i] = cosf(a);
  st[i] = sinf(a);
}

// ---------------- 3-term split GEMM core: C=(Ah+Al)(Bh+Bl), 128x128xBK32 -----
DEV void gemm3_core(const u16* __restrict__ Ah, const u16* __restrict__ Al,
                    const u16* __restrict__ Bh, const u16* __restrict__ Bl,
                    int K, int m0, u16* LAh, u16* LAl, u16* LBh, u16* LBl,
                    f32x4 acc[4][4], int tid)
{
  const int lane = tid & 63, wave = tid >> 6;
  const int wr = wave >> 1, wc = wave & 1;
  const int l15 = lane & 15, l4 = lane >> 4;
  const int nsteps = K >> 5;
  for (int kt = 0; kt < nsteps; ++kt) {
    const int kb = kt << 5;
#pragma unroll
    for (int c = 0; c < 2; ++c) {
      int chunk = c * 256 + tid;
      int row = chunk >> 2, kc = (chunk & 3) << 3;
      size_t aoff = (size_t)(m0 + row) * K + kb + kc;
      size_t boff = (size_t)row * K + kb + kc;
      char* ldst = (char*)0 + c * 4096 + wave * 1024;
      GL2LDS(Ah + aoff, (char*)LAh + (size_t)ldst);
      GL2LDS(Al + aoff, (char*)LAl + (size_t)ldst);
      GL2LDS(Bh + boff, (char*)LBh + (size_t)ldst);
      GL2LDS(Bl + boff, (char*)LBl + (size_t)ldst);
    }
    __syncthreads();
    s16x8 ah[4], al[4], bh[4], bl[4];
#pragma unroll
    for (int i = 0; i < 4; ++i) {
      int ar = (wr * 64 + i * 16 + l15) * 32 + l4 * 8;
      int br = (wc * 64 + i * 16 + l15) * 32 + l4 * 8;
      ah[i] = *(const s16x8*)&LAh[ar];
      al[i] = *(const s16x8*)&LAl[ar];
      bh[i] = *(const s16x8*)&LBh[br];
      bl[i] = *(const s16x8*)&LBl[br];
    }
#pragma unroll
    for (int i = 0; i < 4; ++i)
#pragma unroll
      for (int j = 0; j < 4; ++j) {
        acc[i][j] = __builtin_amdgcn_mfma_f32_16x16x32_bf16(ah[i], bh[j], acc[i][j], 0, 0, 0);
        acc[i][j] = __builtin_amdgcn_mfma_f32_16x16x32_bf16(ah[i], bl[j], acc[i][j], 0, 0, 0);
        acc[i][j] = __builtin_amdgcn_mfma_f32_16x16x32_bf16(al[i], bh[j], acc[i][j], 0, 0, 0);
      }
    __syncthreads();
  }
}

// ---------------- GEMM(q,k,v): x @ W^T, near-fp32; q,k fp32 out; v split -----
__global__ __launch_bounds__(256, 2) void gemm_qkv_k(
    const u16* __restrict__ xh, const u16* __restrict__ xl,
    const u16* __restrict__ wqh, const u16* __restrict__ wql,
    const u16* __restrict__ wkh, const u16* __restrict__ wkl,
    const u16* __restrict__ wvh, const u16* __restrict__ wvl,
    float* __restrict__ Qf, float* __restrict__ Kf,
    u16* __restrict__ vth, u16* __restrict__ vtl)
{
  __shared__ u16 LAh[4096], LAl[4096], LBh[4096], LBl[4096];
  const int m0 = blockIdx.x * 128;
  const int nt = blockIdx.y;
  const u16 *Bh, *Bl; int seg, nl0;
  if (nt < 8)       { Bh = wqh + (size_t)nt * 131072;        Bl = wql + (size_t)nt * 131072;        seg = 0; nl0 = nt * 128; }
  else if (nt < 16) { Bh = wkh + (size_t)(nt - 8) * 131072;  Bl = wkl + (size_t)(nt - 8) * 131072;  seg = 1; nl0 = (nt - 8) * 128; }
  else              { Bh = wvh + (size_t)(nt - 16) * 131072; Bl = wvl + (size_t)(nt - 16) * 131072; seg = 2; nl0 = (nt - 16) * 128; }

  f32x4 acc[4][4];
#pragma unroll
  for (int i = 0; i < 4; ++i)
#pragma unroll
    for (int j = 0; j < 4; ++j) acc[i][j] = (f32x4){0.f, 0.f, 0.f, 0.f};

  const int tid = threadIdx.x;
  gemm3_core(xh, xl, Bh, Bl, 1024, m0, LAh, LAl, LBh, LBl, acc, tid);

  const int lane = tid & 63, wave = tid >> 6;
  const int wr = wave >> 1, wc = wave & 1;
  const int l15 = lane & 15, l4 = lane >> 4;
#pragma unroll
  for (int i = 0; i < 4; ++i) {
    int rowb = m0 + wr * 64 + i * 16 + l4 * 4;
    int b_ = rowb >> 11, trow = rowb & 2047;
#pragma unroll
    for (int j = 0; j < 4; ++j) {
      int col = nl0 + wc * 64 + j * 16 + l15;
      f32x4 v = acc[i][j];
      if (seg <= 1) {          // q/k -> fp32 (b,h,t,d)
        int h_ = col >> 8, d_ = col & 255;
        float* dst = (seg == 0 ? Qf : Kf) + ((size_t)((b_ * 4 + h_) * 2048 + trow)) * 256 + d_;
#pragma unroll
        for (int r = 0; r < 4; ++r) dst[(size_t)r * 256] = v[r];
      } else {                 // v -> (b,h,d,t) split hi/lo bf16
        int h_ = col >> 9, d_ = col & 511;
        size_t base = ((size_t)((b_ * 4 + h_) * 512 + d_)) * 2048 + trow;
        s16x4 hv, lv;
#pragma unroll
        for (int r = 0; r < 4; ++r) {
          u16 hi = f2bf(v[r]);
          hv[r] = (short)hi;
          lv[r] = (short)f2bf(v[r] - bf2f(hi));
        }
        *(s16x4*)(vth + base) = hv;
        *(s16x4*)(vtl + base) = lv;
      }
    }
  }
}

// ---------------- GEMM(gate): silu(x @ Wg^T)*gw -> bf16 (bt, hdv) ------------
__global__ __launch_bounds__(256, 2) void gemm_gate_k(
    const u16* __restrict__ xh, const u16* __restrict__ xl,
    const u16* __restrict__ wgh, const u16* __restrict__ wgl,
    const float* __restrict__ gw, u16* __restrict__ gateb)
{
  __shared__ u16 LAh[4096], LAl[4096], LBh[4096], LBl[4096];
  const int m0 = blockIdx.x * 128;
  const int nl0 = blockIdx.y * 128;
  f32x4 acc[4][4];
#pragma unroll
  for (int i = 0; i < 4; ++i)
#pragma unroll
    for (int j = 0; j < 4; ++j) acc[i][j] = (f32x4){0.f, 0.f, 0.f, 0.f};
  const int tid = threadIdx.x;
  gemm3_core(xh, xl, wgh + (size_t)blockIdx.y * 131072, wgl + (size_t)blockIdx.y * 131072,
             1024, m0, LAh, LAl, LBh, LBl, acc, tid);
  const int lane = tid & 63, wave = tid >> 6;
  const int wr = wave >> 1, wc = wave & 1;
  const int l15 = lane & 15, l4 = lane >> 4;
#pragma unroll
  for (int i = 0; i < 4; ++i) {
    int rowb = m0 + wr * 64 + i * 16 + l4 * 4;
#pragma unroll
    for (int j = 0; j < 4; ++j) {
      int col = nl0 + wc * 64 + j * 16 + l15;
      float gwv = gw[col & 511];
#pragma unroll
      for (int r = 0; r < 4; ++r) {
        float g = acc[i][j][r];
        float gate = g / (1.0f + expf(-g)) * gwv;
        gateb[(size_t)(rowb + r) * 2048 + col] = f2bf(gate);
      }
    }
  }
}

// ---------------- RoPE fp32 -> in-place split bf16 [hi 256 | lo 256] ---------
// one wave per row; q rows scaled by dk^-0.5
__global__ __launch_bounds__(256) void rope_split_k(
    float* __restrict__ Qf, float* __restrict__ Kf,
    const float* __restrict__ ct, const float* __restrict__ st)
{
  int row = blockIdx.x * 4 + (threadIdx.x >> 6);   // 0..32767
  int lane = threadIdx.x & 63;
  float* base; float scale; int r = row;
  if (r < 16384) { base = Qf; scale = 0.0625f; }
  else { r -= 16384; base = Kf; scale = 1.0f; }
  int t = r & 2047;
  float* p = base + (size_t)r * 256;
  f32x4 v = *(const f32x4*)(p + lane * 4);
  int j0 = (lane & 31) * 4;
  f32x4 c = *(const f32x4*)(ct + t * 128 + j0);
  f32x4 s = *(const f32x4*)(st + t * 128 + j0);
  f32x4 sw, o;
#pragma unroll
  for (int q = 0; q < 4; ++q) sw[q] = __shfl_xor(v[q], 32);
#pragma unroll
  for (int q = 0; q < 4; ++q)
    o[q] = (lane < 32 ? v[q] * c[q] - sw[q] * s[q]
                      : sw[q] * s[q] + v[q] * c[q]) * scale;
  s16x4 hi4, lo4;
#pragma unroll
  for (int q = 0; q < 4; ++q) {
    u16 hi = f2bf(o[q]);
    hi4[q] = (short)hi;
    lo4[q] = (short)f2bf(o[q] - bf2f(hi));
  }
  u16* ub = (u16*)p;
  int dd = j0 + ((lane >> 5) << 7);
  *(s16x4*)(ub + dd) = hi4;          // hi plane [0,256)
  *(s16x4*)(ub + 256 + dd) = lo4;    // lo plane [256,512)
}

// ---------------- Retention + fused RMS-norm -> o_n bf16 ---------------------
// QBLK=32, 4 waves (sf,tf) — r8-proven structure (8 waves/CU).
// NEW: bh = bid&7 XCD affinity (round-robin dispatch keeps one (b,h) K/V set
// per XCD L2 — r9 measured FETCH 676->33MB) + tail-balanced qt pairing:
// bid and bid+256 co-reside on a CU; their nkt sums are constant (65).
// 3-term QK^T and PV; K,V read L2-direct; P hi/lo via LDS.
__global__ __launch_bounds__(256, 2) void retention_k(
    const u16* __restrict__ QS, const u16* __restrict__ KS,
    const u16* __restrict__ VTH, const u16* __restrict__ VTL,
    u16* __restrict__ ON)
{
  __shared__ u16 Pldsh[32 * 32];
  __shared__ u16 Pldsl[32 * 32];
  __shared__ float wpart[4][32];
  __shared__ float rmsl[32];

  const int bid = blockIdx.x;
  const int bh = bid & 7;          // XCD affinity under round-robin dispatch
  const int j = bid >> 3;          // 0..63
  const int qt = (j < 32) ? j : 95 - j;   // pair (j, j+32): nkt sum = 65
  const int t0 = qt * 32;
  const int h = bh & 3;
  const float ld = log1pf(-exp2f(-5.0f - (float)h));
  const float c2 = ld * 1.44269504f;

  const int tid = threadIdx.x;
  const int lane = tid & 63, wave = tid >> 6;
  const int l15 = lane & 15, l4 = lane >> 4;
  const int sf = wave & 1, tf = wave >> 1;

  // Q fragments (hi/lo) for this wave's t-quadrant
  s16x8 qfh[8], qfl[8];
  {
    const u16* qrow = QS + (size_t)(bh * 2048 + t0 + tf * 16 + l15) * 512 + l4 * 8;
#pragma unroll
    for (int kf = 0; kf < 8; ++kf) {
      qfh[kf] = *(const s16x8*)(qrow + kf * 32);
      qfl[kf] = *(const s16x8*)(qrow + kf * 32 + 256);
    }
  }

  const u16* kbase = KS + (size_t)(bh * 2048) * 512;
  const u16* vbh = VTH + (size_t)(bh * 512 + wave * 128) * 2048;
  const u16* vbl = VTL + (size_t)(bh * 512 + wave * 128) * 2048;

  f32x4 oacc[2][8];
#pragma unroll
  for (int i = 0; i < 2; ++i)
#pragma unroll
    for (int j2 = 0; j2 < 8; ++j2) oacc[i][j2] = (f32x4){0.f, 0.f, 0.f, 0.f};

  for (int kt = 0; kt <= qt; ++kt) {
    const int s0 = kt * 32;
    // S^T quadrant: D[s][t] = sum_k K[s][k] Q[t][k], 3-term split
    f32x4 sacc = (f32x4){0.f, 0.f, 0.f, 0.f};
    const u16* krow = kbase + (size_t)(s0 + sf * 16 + l15) * 512 + l4 * 8;
#pragma unroll
    for (int kf = 0; kf < 8; ++kf) {
      s16x8 kh = *(const s16x8*)(krow + kf * 32);
      s16x8 kl = *(const s16x8*)(krow + kf * 32 + 256);
      sacc = __builtin_amdgcn_mfma_f32_16x16x32_bf16(kh, qfh[kf], sacc, 0, 0, 0);
      sacc = __builtin_amdgcn_mfma_f32_16x16x32_bf16(kh, qfl[kf], sacc, 0, 0, 0);
      sacc = __builtin_amdgcn_mfma_f32_16x16x32_bf16(kl, qfh[kf], sacc, 0, 0, 0);
    }
    // decay + split P
    const int tl = tf * 16 + l15;
    const int tg = t0 + tl;
    s16x4 pvh, pvl;
#pragma unroll
    for (int r = 0; r < 4; ++r) {
      int sl = sf * 16 + l4 * 4 + r;
      int diff = tg - (s0 + sl);
      float f = (diff >= 0) ? sacc[r] * exp2f(c2 * (float)diff) : 0.0f;
      u16 hi = f2bf(f);
      pvh[r] = (short)hi;
      pvl[r] = (short)f2bf(f - bf2f(hi));
    }
    __syncthreads();   // prior P reads done
    int pboff = ((tl * 64 + (sf * 16 + l4 * 4) * 2) ^ ((tl & 7) << 4));
    *(s16x4*)((char*)Pldsh + pboff) = pvh;
    *(s16x4*)((char*)Pldsl + pboff) = pvl;
    __syncthreads();
    // PV: O[t][d] += P[t][s] * Vt[d][s], 3-term; wave owns d in [wave*128,+128)
    s16x8 pah[2], pal[2];
#pragma unroll
    for (int mf = 0; mf < 2; ++mf) {
      int prow = mf * 16 + l15;
      int poff = ((prow * 64 + l4 * 16) ^ ((prow & 7) << 4));
      pah[mf] = *(const s16x8*)((char*)Pldsh + poff);
      pal[mf] = *(const s16x8*)((char*)Pldsl + poff);
    }
#pragma unroll
    for (int nf = 0; nf < 8; ++nf) {
      size_t voff = (size_t)(nf * 16 + l15) * 2048 + s0 + l4 * 8;
      s16x8 vh = *(const s16x8*)(vbh + voff);
      s16x8 vl = *(const s16x8*)(vbl + voff);
#pragma unroll
      for (int mf = 0; mf < 2; ++mf) {
        oacc[mf][nf] = __builtin_amdgcn_mfma_f32_16x16x32_bf16(pah[mf], vh, oacc[mf][nf], 0, 0, 0);
        oacc[mf][nf] = __builtin_amdgcn_mfma_f32_16x16x32_bf16(pah[mf], vl, oacc[mf][nf], 0, 0, 0);
        oacc[mf][nf] = __builtin_amdgcn_mfma_f32_16x16x32_bf16(pal[mf], vh, oacc[mf][nf], 0, 0, 0);
      }
    }
  }
  // fused RMS over dv=512 per t-row, then o_n -> bf16
  float ss[2][4];
#pragma unroll
  for (int mf = 0; mf < 2; ++mf)
#pragma unroll
    for (int r = 0; r < 4; ++r) {
      float a = 0.f;
#pragma unroll
      for (int nf = 0; nf < 8; ++nf) { float o = oacc[mf][nf][r]; a += o * o; }
      ss[mf][r] = a;
    }
#pragma unroll
  for (int m = 1; m < 16; m <<= 1)
#pragma unroll
    for (int mf = 0; mf < 2; ++mf)
#pragma unroll
      for (int r = 0; r < 4; ++r) ss[mf][r] += __shfl_xor(ss[mf][r], m);
  if (l15 == 0) {
#pragma unroll
    for (int mf = 0; mf < 2; ++mf)
#pragma unroll
      for (int r = 0; r < 4; ++r) wpart[wave][mf * 16 + l4 * 4 + r] = ss[mf][r];
  }
  __syncthreads();
  if (tid < 32)
    rmsl[tid] = rsqrtf((wpart[0][tid] + wpart[1][tid] + wpart[2][tid] + wpart[3][tid])
                       * (1.0f / 512.0f) + 1e-5f);
  __syncthreads();
  u16* ob = ON + (size_t)(bh * 2048 + t0) * 512;
#pragma unroll
  for (int mf = 0; mf < 2; ++mf)
#pragma unroll
    for (int r = 0; r < 4; ++r) {
      int trow = mf * 16 + l4 * 4 + r;
      float rr = rmsl[trow];
#pragma unroll
      for (int nf = 0; nf < 8; ++nf)
        ob[(size_t)trow * 512 + wave * 128 + nf * 16 + l15] = f2bf(oacc[mf][nf][r] * rr);
    }
}

// ---------------- og = o_n * gate -> split hi/lo (bt, hdv) layout ------------
__global__ __launch_bounds__(256) void og_k(
    const u16* __restrict__ ON, const u16* __restrict__ gateb,
    u16* __restrict__ ogh, u16* __restrict__ ogl)
{
  size_t i = ((size_t)blockIdx.x * 256 + threadIdx.x) * 8;
  int d = (int)(i & 511);
  int t = (int)((i >> 9) & 2047);
  int bh = (int)(i >> 20);
  int h = bh & 3, b = bh >> 2;
  size_t gidx = ((size_t)(b * 2048 + t)) * 2048 + h * 512 + d;
  s16x8 o8 = *(const s16x8*)(ON + i);
  s16x8 g8 = *(const s16x8*)(gateb + gidx);
  s16x8 rh, rl;
#pragma unroll
  for (int j = 0; j < 8; ++j) {
    float p = bf2f((u16)o8[j]) * bf2f((u16)g8[j]);
    u16 hi = f2bf(p);
    rh[j] = (short)hi;
    rl[j] = (short)f2bf(p - bf2f(hi));
  }
  *(s16x8*)(ogh + gidx) = rh;
  *(s16x8*)(ogl + gidx) = rl;
}

// ---------------- GEMM2: (og_h+og_l) @ (Wo_h+Wo_l)^T -> out fp32 -------------
__global__ __launch_bounds__(256, 2) void gemm_out_k(
    const u16* __restrict__ OGh, const u16* __restrict__ OGl,
    const u16* __restrict__ WOh, const u16* __restrict__ WOl,
    float* __restrict__ OUT)
{
  __shared__ u16 LAh[4096], LAl[4096], LBh[4096], LBl[4096];
  const int m0 = blockIdx.x * 128;
  const int n0 = blockIdx.y * 128;
  f32x4 acc[4][4];
#pragma unroll
  for (int i = 0; i < 4; ++i)
#pragma unroll
    for (int j = 0; j < 4; ++j) acc[i][j] = (f32x4){0.f, 0.f, 0.f, 0.f};
  const int tid = threadIdx.x;
  gemm3_core(OGh, OGl, WOh + (size_t)n0 * 2048, WOl + (size_t)n0 * 2048,
             2048, m0, LAh, LAl, LBh, LBl, acc, tid);
  const int lane = tid & 63, wave = tid >> 6;
  const int wr = wave >> 1, wc = wave & 1;
  const int l15 = lane & 15, l4 = lane >> 4;
#pragma unroll
  for (int i = 0; i < 4; ++i) {
    int rowb = m0 + wr * 64 + i * 16 + l4 * 4;
#pragma unroll
    for (int j = 0; j < 4; ++j) {
      int col = n0 + wc * 64 + j * 16 + l15;
#pragma unroll
      for (int r = 0; r < 4; ++r)
        OUT[(size_t)(rowb + r) * 1024 + col] = acc[i][j][r];
    }
  }
}

// ---------------- launch ----------------
extern "C" void kernel_launch(void* const* d_in, const int* in_sizes, int n_in,
                              void* d_out, int out_size, void* d_ws, size_t ws_size,
                              hipStream_t stream)
{
  (void)in_sizes; (void)n_in; (void)out_size; (void)ws_size;
  const float* x  = (const float*)d_in[0];
  const float* wq = (const float*)d_in[1];
  const float* wk = (const float*)d_in[2];
  const float* wv = (const float*)d_in[3];
  const float* wg = (const float*)d_in[4];
  const float* wo = (const float*)d_in[5];
  const float* gw = (const float*)d_in[6];
  char* ws = (char*)d_ws;
#define MB(x) ((size_t)(x) * 1048576)
  // persistent regions (peak 112 MB)
  u16* xh  = (u16*)(ws + MB(0));    // dies after gemm_gate
  u16* xl  = (u16*)(ws + MB(8));
  u16* wqh = (u16*)(ws + MB(16));   // wq/wk/wv die after gemm_qkv
  u16* wql = (u16*)(ws + MB(18));
  u16* wkh = (u16*)(ws + MB(20));
  u16* wkl = (u16*)(ws + MB(22));
  u16* wvh = (u16*)(ws + MB(24));
  u16* wvl = (u16*)(ws + MB(28));
  u16* wgh = (u16*)(ws + MB(32));   // dies after gemm_gate
  u16* wgl = (u16*)(ws + MB(36));
  u16* woh = (u16*)(ws + MB(40));   // to end
  u16* wol = (u16*)(ws + MB(44));
  float* Qf = (float*)(ws + MB(48)); // fp32 -> split-in-place; dies after retention
  float* Kf = (float*)(ws + MB(64));
  u16* vth = (u16*)(ws + MB(80));   // dies after retention
  u16* vtl = (u16*)(ws + MB(96));
  // aliases over dead regions
  u16* gateb = (u16*)(ws + MB(16)); // over wq/wk/wv after gemm_qkv; dies after og_k
  float* ct  = (float*)(ws + MB(32)); // over wgh after gemm_gate; dies after rope
  float* st  = (float*)(ws + MB(33));
  u16* onb   = (u16*)(ws + MB(0));  // o_n over x after gemm_gate; dies after og_k
  u16* ogh   = (u16*)(ws + MB(48)); // over Qf/Kf after retention; to gemm_out
  u16* ogl   = (u16*)(ws + MB(64));
  u16* qs = (u16*)(ws + MB(48));    // split q/k views (in-place over Qf/Kf)
  u16* ks = (u16*)(ws + MB(64));
  float* out = (float*)d_out;

  cvt_split_k<<<6144, 256, 0, stream>>>(x, wq, wk, wv, wg, wo,
      xh, xl, wqh, wql, wkh, wkl, wvh, wvl, wgh, wgl, woh, wol);
  gemm_qkv_k<<<dim3(32, 32), 256, 0, stream>>>(xh, xl, wqh, wql, wkh, wkl, wvh, wvl,
      Qf, Kf, vth, vtl);
  gemm_gate_k<<<dim3(32, 16), 256, 0, stream>>>(xh, xl, wgh, wgl, gw, gateb);
  rope_table_k<<<1024, 256, 0, stream>>>(ct, st);
  rope_split_k<<<8192, 256, 0, stream>>>(Qf, Kf, ct, st);
  retention_k<<<512, 256, 0, stream>>>(qs, ks, vth, vtl, onb);
  og_k<<<4096, 256, 0, stream>>>(onb, gateb, ogh, ogl);
  gemm_out_k<<<dim3(32, 8), 256, 0, stream>>>(ogh, ogl, woh, wol, out);
#undef MB
}

// Round 11
// 609.273 us; speedup vs baseline: 1.3865x; 1.0887x over previous
//
#include <hip/hip_runtime.h>
#include <stdint.h>

typedef unsigned short u16;
typedef __attribute__((ext_vector_type(8))) short s16x8;   // 8 bf16 = 4 VGPR
typedef __attribute__((ext_vector_type(4))) short s16x4;
typedef __attribute__((ext_vector_type(4))) float f32x4;

#define DEV static __device__ __forceinline__

DEV u16 f2bf(float f) {
  union { float f; unsigned u; } v; v.f = f;
  unsigned u = v.u;
  u += 0x7fffu + ((u >> 16) & 1u);   // RNE
  return (u16)(u >> 16);
}
DEV float bf2f(u16 h) {
  union { unsigned u; float f; } v; v.u = ((unsigned)h) << 16;
  return v.f;
}

#define GL2LDS(gp, lp) __builtin_amdgcn_global_load_lds( \
    (const __attribute__((address_space(1))) unsigned int*)(const void*)(gp), \
    (__attribute__((address_space(3))) unsigned int*)(void*)(lp), 16, 0, 0)

// dims: B=2 T=2048 DM=1024 H=4 DK=256 DV=512; BT=4096
// Precision: GEMMs 3-term split-bf16 (near-fp32). Retention spends margin:
// 2-term QK^T (K single-bf16), 1-term PV (P,V single-bf16). Measured base
// absmax 0.0078 @ threshold 0.0348; predicted ~0.012 after this change.

// ---------------- split ALL inputs into bf16 hi/lo ----------------
__global__ __launch_bounds__(256) void cvt_split_k(
    const float* __restrict__ x,  const float* __restrict__ wq,
    const float* __restrict__ wk, const float* __restrict__ wv,
    const float* __restrict__ wg, const float* __restrict__ wo,
    u16* __restrict__ xh,  u16* __restrict__ xl,
    u16* __restrict__ wqh, u16* __restrict__ wql,
    u16* __restrict__ wkh, u16* __restrict__ wkl,
    u16* __restrict__ wvh, u16* __restrict__ wvl,
    u16* __restrict__ wgh, u16* __restrict__ wgl,
    u16* __restrict__ woh, u16* __restrict__ wol)
{
  long e = ((long)blockIdx.x * 256 + threadIdx.x) * 8;
  const float* src; u16 *dh, *dl;
  if (e < 4194304L)                    { src = x;  dh = xh;  dl = xl;  }
  else if ((e -= 4194304L) < 1048576L) { src = wq; dh = wqh; dl = wql; }
  else if ((e -= 1048576L) < 1048576L) { src = wk; dh = wkh; dl = wkl; }
  else if ((e -= 1048576L) < 2097152L) { src = wv; dh = wvh; dl = wvl; }
  else if ((e -= 2097152L) < 2097152L) { src = wg; dh = wgh; dl = wgl; }
  else                  { e -= 2097152L; src = wo; dh = woh; dl = wol; }
  f32x4 a = *(const f32x4*)(src + e);
  f32x4 b = *(const f32x4*)(src + e + 4);
  float f[8] = {a[0], a[1], a[2], a[3], b[0], b[1], b[2], b[3]};
  s16x8 rh, rl;
#pragma unroll
  for (int j = 0; j < 8; ++j) {
    u16 hi = f2bf(f[j]);
    rh[j] = (short)hi;
    rl[j] = (short)f2bf(f[j] - bf2f(hi));
  }
  *(s16x8*)(dh + e) = rh;
  *(s16x8*)(dl + e) = rl;
}

// ---------------- RoPE table: cos/sin [T=2048][128] ----------------
__global__ __launch_bounds__(256) void rope_table_k(float* __restrict__ ct, float* __restrict__ st)
{
  int i = blockIdx.x * 256 + threadIdx.x;     // 262144
  int t = i >> 7, j = i & 127;
  float freq = powf(10000.0f, -(float)j * (1.0f / 128.0f));
  float a = (float)t * freq;
  ct[i] = cosf(a);
  st[i] = sinf(a);
}

// ---------------- 3-term split GEMM core: C=(Ah+Al)(Bh+Bl), 128x128xBK32 -----
DEV void gemm3_core(const u16* __restrict__ Ah, const u16* __restrict__ Al,
                    const u16* __restrict__ Bh, const u16* __restrict__ Bl,
                    int K, int m0, u16* LAh, u16* LAl, u16* LBh, u16* LBl,
                    f32x4 acc[4][4], int tid)
{
  const int lane = tid & 63, wave = tid >> 6;
  const int wr = wave >> 1, wc = wave & 1;
  const int l15 = lane & 15, l4 = lane >> 4;
  const int nsteps = K >> 5;
  for (int kt = 0; kt < nsteps; ++kt) {
    const int kb = kt << 5;
#pragma unroll
    for (int c = 0; c < 2; ++c) {
      int chunk = c * 256 + tid;
      int row = chunk >> 2, kc = (chunk & 3) << 3;
      size_t aoff = (size_t)(m0 + row) * K + kb + kc;
      size_t boff = (size_t)row * K + kb + kc;
      char* ldst = (char*)0 + c * 4096 + wave * 1024;
      GL2LDS(Ah + aoff, (char*)LAh + (size_t)ldst);
      GL2LDS(Al + aoff, (char*)LAl + (size_t)ldst);
      GL2LDS(Bh + boff, (char*)LBh + (size_t)ldst);
      GL2LDS(Bl + boff, (char*)LBl + (size_t)ldst);
    }
    __syncthreads();
    s16x8 ah[4], al[4], bh[4], bl[4];
#pragma unroll
    for (int i = 0; i < 4; ++i) {
      int ar = (wr * 64 + i * 16 + l15) * 32 + l4 * 8;
      int br = (wc * 64 + i * 16 + l15) * 32 + l4 * 8;
      ah[i] = *(const s16x8*)&LAh[ar];
      al[i] = *(const s16x8*)&LAl[ar];
      bh[i] = *(const s16x8*)&LBh[br];
      bl[i] = *(const s16x8*)&LBl[br];
    }
#pragma unroll
    for (int i = 0; i < 4; ++i)
#pragma unroll
      for (int j = 0; j < 4; ++j) {
        acc[i][j] = __builtin_amdgcn_mfma_f32_16x16x32_bf16(ah[i], bh[j], acc[i][j], 0, 0, 0);
        acc[i][j] = __builtin_amdgcn_mfma_f32_16x16x32_bf16(ah[i], bl[j], acc[i][j], 0, 0, 0);
        acc[i][j] = __builtin_amdgcn_mfma_f32_16x16x32_bf16(al[i], bh[j], acc[i][j], 0, 0, 0);
      }
    __syncthreads();
  }
}

// ---------------- GEMM(q,k,v): x @ W^T, near-fp32; q,k fp32 out; v split -----
__global__ __launch_bounds__(256, 2) void gemm_qkv_k(
    const u16* __restrict__ xh, const u16* __restrict__ xl,
    const u16* __restrict__ wqh, const u16* __restrict__ wql,
    const u16* __restrict__ wkh, const u16* __restrict__ wkl,
    const u16* __restrict__ wvh, const u16* __restrict__ wvl,
    float* __restrict__ Qf, float* __restrict__ Kf,
    u16* __restrict__ vth, u16* __restrict__ vtl)
{
  __shared__ u16 LAh[4096], LAl[4096], LBh[4096], LBl[4096];
  const int m0 = blockIdx.x * 128;
  const int nt = blockIdx.y;
  const u16 *Bh, *Bl; int seg, nl0;
  if (nt < 8)       { Bh = wqh + (size_t)nt * 131072;        Bl = wql + (size_t)nt * 131072;        seg = 0; nl0 = nt * 128; }
  else if (nt < 16) { Bh = wkh + (size_t)(nt - 8) * 131072;  Bl = wkl + (size_t)(nt - 8) * 131072;  seg = 1; nl0 = (nt - 8) * 128; }
  else              { Bh = wvh + (size_t)(nt - 16) * 131072; Bl = wvl + (size_t)(nt - 16) * 131072; seg = 2; nl0 = (nt - 16) * 128; }

  f32x4 acc[4][4];
#pragma unroll
  for (int i = 0; i < 4; ++i)
#pragma unroll
    for (int j = 0; j < 4; ++j) acc[i][j] = (f32x4){0.f, 0.f, 0.f, 0.f};

  const int tid = threadIdx.x;
  gemm3_core(xh, xl, Bh, Bl, 1024, m0, LAh, LAl, LBh, LBl, acc, tid);

  const int lane = tid & 63, wave = tid >> 6;
  const int wr = wave >> 1, wc = wave & 1;
  const int l15 = lane & 15, l4 = lane >> 4;
#pragma unroll
  for (int i = 0; i < 4; ++i) {
    int rowb = m0 + wr * 64 + i * 16 + l4 * 4;
    int b_ = rowb >> 11, trow = rowb & 2047;
#pragma unroll
    for (int j = 0; j < 4; ++j) {
      int col = nl0 + wc * 64 + j * 16 + l15;
      f32x4 v = acc[i][j];
      if (seg <= 1) {          // q/k -> fp32 (b,h,t,d)
        int h_ = col >> 8, d_ = col & 255;
        float* dst = (seg == 0 ? Qf : Kf) + ((size_t)((b_ * 4 + h_) * 2048 + trow)) * 256 + d_;
#pragma unroll
        for (int r = 0; r < 4; ++r) dst[(size_t)r * 256] = v[r];
      } else {                 // v -> (b,h,d,t) split hi/lo bf16
        int h_ = col >> 9, d_ = col & 511;
        size_t base = ((size_t)((b_ * 4 + h_) * 512 + d_)) * 2048 + trow;
        s16x4 hv, lv;
#pragma unroll
        for (int r = 0; r < 4; ++r) {
          u16 hi = f2bf(v[r]);
          hv[r] = (short)hi;
          lv[r] = (short)f2bf(v[r] - bf2f(hi));
        }
        *(s16x4*)(vth + base) = hv;
        *(s16x4*)(vtl + base) = lv;
      }
    }
  }
}

// ---------------- GEMM(gate): silu(x @ Wg^T)*gw -> bf16 (bt, hdv) ------------
__global__ __launch_bounds__(256, 2) void gemm_gate_k(
    const u16* __restrict__ xh, const u16* __restrict__ xl,
    const u16* __restrict__ wgh, const u16* __restrict__ wgl,
    const float* __restrict__ gw, u16* __restrict__ gateb)
{
  __shared__ u16 LAh[4096], LAl[4096], LBh[4096], LBl[4096];
  const int m0 = blockIdx.x * 128;
  const int nl0 = blockIdx.y * 128;
  f32x4 acc[4][4];
#pragma unroll
  for (int i = 0; i < 4; ++i)
#pragma unroll
    for (int j = 0; j < 4; ++j) acc[i][j] = (f32x4){0.f, 0.f, 0.f, 0.f};
  const int tid = threadIdx.x;
  gemm3_core(xh, xl, wgh + (size_t)blockIdx.y * 131072, wgl + (size_t)blockIdx.y * 131072,
             1024, m0, LAh, LAl, LBh, LBl, acc, tid);
  const int lane = tid & 63, wave = tid >> 6;
  const int wr = wave >> 1, wc = wave & 1;
  const int l15 = lane & 15, l4 = lane >> 4;
#pragma unroll
  for (int i = 0; i < 4; ++i) {
    int rowb = m0 + wr * 64 + i * 16 + l4 * 4;
#pragma unroll
    for (int j = 0; j < 4; ++j) {
      int col = nl0 + wc * 64 + j * 16 + l15;
      float gwv = gw[col & 511];
#pragma unroll
      for (int r = 0; r < 4; ++r) {
        float g = acc[i][j][r];
        float gate = g / (1.0f + expf(-g)) * gwv;
        gateb[(size_t)(rowb + r) * 2048 + col] = f2bf(gate);
      }
    }
  }
}

// ---------------- RoPE fp32 -> in-place split bf16 [hi 256 | lo 256] ---------
// one wave per row; q rows scaled by dk^-0.5
__global__ __launch_bounds__(256) void rope_split_k(
    float* __restrict__ Qf, float* __restrict__ Kf,
    const float* __restrict__ ct, const float* __restrict__ st)
{
  int row = blockIdx.x * 4 + (threadIdx.x >> 6);   // 0..32767
  int lane = threadIdx.x & 63;
  float* base; float scale; int r = row;
  if (r < 16384) { base = Qf; scale = 0.0625f; }
  else { r -= 16384; base = Kf; scale = 1.0f; }
  int t = r & 2047;
  float* p = base + (size_t)r * 256;
  f32x4 v = *(const f32x4*)(p + lane * 4);
  int j0 = (lane & 31) * 4;
  f32x4 c = *(const f32x4*)(ct + t * 128 + j0);
  f32x4 s = *(const f32x4*)(st + t * 128 + j0);
  f32x4 sw, o;
#pragma unroll
  for (int q = 0; q < 4; ++q) sw[q] = __shfl_xor(v[q], 32);
#pragma unroll
  for (int q = 0; q < 4; ++q)
    o[q] = (lane < 32 ? v[q] * c[q] - sw[q] * s[q]
                      : sw[q] * s[q] + v[q] * c[q]) * scale;
  s16x4 hi4, lo4;
#pragma unroll
  for (int q = 0; q < 4; ++q) {
    u16 hi = f2bf(o[q]);
    hi4[q] = (short)hi;
    lo4[q] = (short)f2bf(o[q] - bf2f(hi));
  }
  u16* ub = (u16*)p;
  int dd = j0 + ((lane >> 5) << 7);
  *(s16x4*)(ub + dd) = hi4;          // hi plane [0,256)
  *(s16x4*)(ub + 256 + dd) = lo4;    // lo plane [256,512)
}

// ---------------- Retention + fused RMS-norm -> o_n bf16 ---------------------
// QBLK=32, 4 waves (sf,tf), 512 blocks, XCD affinity bh=bid&7, tail pairing.
// Margin-spending numerics: 2-term QK^T (K single), 1-term PV (P,V single).
// Loads/iter/wave 32->16, MFMA 48->24 vs r10 (latency-bound: time ~ loads).
__global__ __launch_bounds__(256, 2) void retention_k(
    const u16* __restrict__ QS, const u16* __restrict__ KS,
    const u16* __restrict__ VTH, u16* __restrict__ ON)
{
  __shared__ u16 Pldsh[32 * 32];
  __shared__ float wpart[4][32];
  __shared__ float rmsl[32];

  const int bid = blockIdx.x;
  const int bh = bid & 7;          // XCD affinity under round-robin dispatch
  const int j = bid >> 3;          // 0..63
  const int qt = (j < 32) ? j : 95 - j;   // pair (j, j+32): nkt sum = 65
  const int t0 = qt * 32;
  const int h = bh & 3;
  const float ld = log1pf(-exp2f(-5.0f - (float)h));
  const float c2 = ld * 1.44269504f;

  const int tid = threadIdx.x;
  const int lane = tid & 63, wave = tid >> 6;
  const int l15 = lane & 15, l4 = lane >> 4;
  const int sf = wave & 1, tf = wave >> 1;

  // Q fragments (hi/lo) for this wave's t-quadrant
  s16x8 qfh[8], qfl[8];
  {
    const u16* qrow = QS + (size_t)(bh * 2048 + t0 + tf * 16 + l15) * 512 + l4 * 8;
#pragma unroll
    for (int kf = 0; kf < 8; ++kf) {
      qfh[kf] = *(const s16x8*)(qrow + kf * 32);
      qfl[kf] = *(const s16x8*)(qrow + kf * 32 + 256);
    }
  }

  const u16* kbase = KS + (size_t)(bh * 2048) * 512;
  const u16* vbh = VTH + (size_t)(bh * 512 + wave * 128) * 2048;

  f32x4 oacc[2][8];
#pragma unroll
  for (int i = 0; i < 2; ++i)
#pragma unroll
    for (int j2 = 0; j2 < 8; ++j2) oacc[i][j2] = (f32x4){0.f, 0.f, 0.f, 0.f};

  for (int kt = 0; kt <= qt; ++kt) {
    const int s0 = kt * 32;
    // S^T quadrant: D[s][t] = sum_k K[s][k] Q[t][k], 2-term (K hi only)
    f32x4 sacc = (f32x4){0.f, 0.f, 0.f, 0.f};
    const u16* krow = kbase + (size_t)(s0 + sf * 16 + l15) * 512 + l4 * 8;
#pragma unroll
    for (int kf = 0; kf < 8; ++kf) {
      s16x8 kh = *(const s16x8*)(krow + kf * 32);
      sacc = __builtin_amdgcn_mfma_f32_16x16x32_bf16(kh, qfh[kf], sacc, 0, 0, 0);
      sacc = __builtin_amdgcn_mfma_f32_16x16x32_bf16(kh, qfl[kf], sacc, 0, 0, 0);
    }
    // decay + P (single bf16)
    const int tl = tf * 16 + l15;
    const int tg = t0 + tl;
    s16x4 pvh;
#pragma unroll
    for (int r = 0; r < 4; ++r) {
      int sl = sf * 16 + l4 * 4 + r;
      int diff = tg - (s0 + sl);
      float f = (diff >= 0) ? sacc[r] * exp2f(c2 * (float)diff) : 0.0f;
      pvh[r] = (short)f2bf(f);
    }
    __syncthreads();   // prior P reads done
    int pboff = ((tl * 64 + (sf * 16 + l4 * 4) * 2) ^ ((tl & 7) << 4));
    *(s16x4*)((char*)Pldsh + pboff) = pvh;
    __syncthreads();
    // PV: O[t][d] += P[t][s] * Vt[d][s], 1-term; wave owns d in [wave*128,+128)
    s16x8 pah[2];
#pragma unroll
    for (int mf = 0; mf < 2; ++mf) {
      int prow = mf * 16 + l15;
      int poff = ((prow * 64 + l4 * 16) ^ ((prow & 7) << 4));
      pah[mf] = *(const s16x8*)((char*)Pldsh + poff);
    }
#pragma unroll
    for (int nf = 0; nf < 8; ++nf) {
      size_t voff = (size_t)(nf * 16 + l15) * 2048 + s0 + l4 * 8;
      s16x8 vh = *(const s16x8*)(vbh + voff);
#pragma unroll
      for (int mf = 0; mf < 2; ++mf)
        oacc[mf][nf] = __builtin_amdgcn_mfma_f32_16x16x32_bf16(pah[mf], vh, oacc[mf][nf], 0, 0, 0);
    }
  }
  // fused RMS over dv=512 per t-row, then o_n -> bf16
  float ss[2][4];
#pragma unroll
  for (int mf = 0; mf < 2; ++mf)
#pragma unroll
    for (int r = 0; r < 4; ++r) {
      float a = 0.f;
#pragma unroll
      for (int nf = 0; nf < 8; ++nf) { float o = oacc[mf][nf][r]; a += o * o; }
      ss[mf][r] = a;
    }
#pragma unroll
  for (int m = 1; m < 16; m <<= 1)
#pragma unroll
    for (int mf = 0; mf < 2; ++mf)
#pragma unroll
      for (int r = 0; r < 4; ++r) ss[mf][r] += __shfl_xor(ss[mf][r], m);
  if (l15 == 0) {
#pragma unroll
    for (int mf = 0; mf < 2; ++mf)
#pragma unroll
      for (int r = 0; r < 4; ++r) wpart[wave][mf * 16 + l4 * 4 + r] = ss[mf][r];
  }
  __syncthreads();
  if (tid < 32)
    rmsl[tid] = rsqrtf((wpart[0][tid] + wpart[1][tid] + wpart[2][tid] + wpart[3][tid])
                       * (1.0f / 512.0f) + 1e-5f);
  __syncthreads();
  u16* ob = ON + (size_t)(bh * 2048 + t0) * 512;
#pragma unroll
  for (int mf = 0; mf < 2; ++mf)
#pragma unroll
    for (int r = 0; r < 4; ++r) {
      int trow = mf * 16 + l4 * 4 + r;
      float rr = rmsl[trow];
#pragma unroll
      for (int nf = 0; nf < 8; ++nf)
        ob[(size_t)trow * 512 + wave * 128 + nf * 16 + l15] = f2bf(oacc[mf][nf][r] * rr);
    }
}

// ---------------- og = o_n * gate -> split hi/lo (bt, hdv) layout ------------
__global__ __launch_bounds__(256) void og_k(
    const u16* __restrict__ ON, const u16* __restrict__ gateb,
    u16* __restrict__ ogh, u16* __restrict__ ogl)
{
  size_t i = ((size_t)blockIdx.x * 256 + threadIdx.x) * 8;
  int d = (int)(i & 511);
  int t = (int)((i >> 9) & 2047);
  int bh = (int)(i >> 20);
  int h = bh & 3, b = bh >> 2;
  size_t gidx = ((size_t)(b * 2048 + t)) * 2048 + h * 512 + d;
  s16x8 o8 = *(const s16x8*)(ON + i);
  s16x8 g8 = *(const s16x8*)(gateb + gidx);
  s16x8 rh, rl;
#pragma unroll
  for (int j = 0; j < 8; ++j) {
    float p = bf2f((u16)o8[j]) * bf2f((u16)g8[j]);
    u16 hi = f2bf(p);
    rh[j] = (short)hi;
    rl[j] = (short)f2bf(p - bf2f(hi));
  }
  *(s16x8*)(ogh + gidx) = rh;
  *(s16x8*)(ogl + gidx) = rl;
}

// ---------------- GEMM2: (og_h+og_l) @ (Wo_h+Wo_l)^T -> out fp32 -------------
__global__ __launch_bounds__(256, 2) void gemm_out_k(
    const u16* __restrict__ OGh, const u16* __restrict__ OGl,
    const u16* __restrict__ WOh, const u16* __restrict__ WOl,
    float* __restrict__ OUT)
{
  __shared__ u16 LAh[4096], LAl[4096], LBh[4096], LBl[4096];
  const int m0 = blockIdx.x * 128;
  const int n0 = blockIdx.y * 128;
  f32x4 acc[4][4];
#pragma unroll
  for (int i = 0; i < 4; ++i)
#pragma unroll
    for (int j = 0; j < 4; ++j) acc[i][j] = (f32x4){0.f, 0.f, 0.f, 0.f};
  const int tid = threadIdx.x;
  gemm3_core(OGh, OGl, WOh + (size_t)n0 * 2048, WOl + (size_t)n0 * 2048,
             2048, m0, LAh, LAl, LBh, LBl, acc, tid);
  const int lane = tid & 63, wave = tid >> 6;
  const int wr = wave >> 1, wc = wave & 1;
  const int l15 = lane & 15, l4 = lane >> 4;
#pragma unroll
  for (int i = 0; i < 4; ++i) {
    int rowb = m0 + wr * 64 + i * 16 + l4 * 4;
#pragma unroll
    for (int j = 0; j < 4; ++j) {
      int col = n0 + wc * 64 + j * 16 + l15;
#pragma unroll
      for (int r = 0; r < 4; ++r)
        OUT[(size_t)(rowb + r) * 1024 + col] = acc[i][j][r];
    }
  }
}

// ---------------- launch ----------------
extern "C" void kernel_launch(void* const* d_in, const int* in_sizes, int n_in,
                              void* d_out, int out_size, void* d_ws, size_t ws_size,
                              hipStream_t stream)
{
  (void)in_sizes; (void)n_in; (void)out_size; (void)ws_size;
  const float* x  = (const float*)d_in[0];
  const float* wq = (const float*)d_in[1];
  const float* wk = (const float*)d_in[2];
  const float* wv = (const float*)d_in[3];
  const float* wg = (const float*)d_in[4];
  const float* wo = (const float*)d_in[5];
  const float* gw = (const float*)d_in[6];
  char* ws = (char*)d_ws;
#define MB(x) ((size_t)(x) * 1048576)
  // persistent regions (peak 112 MB)
  u16* xh  = (u16*)(ws + MB(0));    // dies after gemm_gate
  u16* xl  = (u16*)(ws + MB(8));
  u16* wqh = (u16*)(ws + MB(16));   // wq/wk/wv die after gemm_qkv
  u16* wql = (u16*)(ws + MB(18));
  u16* wkh = (u16*)(ws + MB(20));
  u16* wkl = (u16*)(ws + MB(22));
  u16* wvh = (u16*)(ws + MB(24));
  u16* wvl = (u16*)(ws + MB(28));
  u16* wgh = (u16*)(ws + MB(32));   // dies after gemm_gate
  u16* wgl = (u16*)(ws + MB(36));
  u16* woh = (u16*)(ws + MB(40));   // to end
  u16* wol = (u16*)(ws + MB(44));
  float* Qf = (float*)(ws + MB(48)); // fp32 -> split-in-place; dies after retention
  float* Kf = (float*)(ws + MB(64));
  u16* vth = (u16*)(ws + MB(80));   // dies after retention
  u16* vtl = (u16*)(ws + MB(96));
  // aliases over dead regions
  u16* gateb = (u16*)(ws + MB(16)); // over wq/wk/wv after gemm_qkv; dies after og_k
  float* ct  = (float*)(ws + MB(32)); // over wgh after gemm_gate; dies after rope
  float* st  = (float*)(ws + MB(33));
  u16* onb   = (u16*)(ws + MB(0));  // o_n over x after gemm_gate; dies after og_k
  u16* ogh   = (u16*)(ws + MB(48)); // over Qf/Kf after retention; to gemm_out
  u16* ogl   = (u16*)(ws + MB(64));
  u16* qs = (u16*)(ws + MB(48));    // split q/k views (in-place over Qf/Kf)
  u16* ks = (u16*)(ws + MB(64));
  float* out = (float*)d_out;

  cvt_split_k<<<6144, 256, 0, stream>>>(x, wq, wk, wv, wg, wo,
      xh, xl, wqh, wql, wkh, wkl, wvh, wvl, wgh, wgl, woh, wol);
  gemm_qkv_k<<<dim3(32, 32), 256, 0, stream>>>(xh, xl, wqh, wql, wkh, wkl, wvh, wvl,
      Qf, Kf, vth, vtl);
  gemm_gate_k<<<dim3(32, 16), 256, 0, stream>>>(xh, xl, wgh, wgl, gw, gateb);
  rope_table_k<<<1024, 256, 0, stream>>>(ct, st);
  rope_split_k<<<8192, 256, 0, stream>>>(Qf, Kf, ct, st);
  retention_k<<<512, 256, 0, stream>>>(qs, ks, vth, onb);
  og_k<<<4096, 256, 0, stream>>>(onb, gateb, ogh, ogl);
  gemm_out_k<<<dim3(32, 8), 256, 0, stream>>>(ogh, ogl, woh, wol, out);
#undef MB
}

// Round 12
// 491.723 us; speedup vs baseline: 1.7179x; 1.2391x over previous
//
#include <hip/hip_runtime.h>
#include <stdint.h>

typedef unsigned short u16;
typedef __attribute__((ext_vector_type(8))) short s16x8;   // 8 bf16 = 4 VGPR
typedef __attribute__((ext_vector_type(4))) short s16x4;
typedef __attribute__((ext_vector_type(4))) float f32x4;

#define DEV static __device__ __forceinline__

DEV u16 f2bf(float f) {
  union { float f; unsigned u; } v; v.f = f;
  unsigned u = v.u;
  u += 0x7fffu + ((u >> 16) & 1u);   // RNE
  return (u16)(u >> 16);
}
DEV float bf2f(u16 h) {
  union { unsigned u; float f; } v; v.u = ((unsigned)h) << 16;
  return v.f;
}

#define GL2LDS(gp, lp) __builtin_amdgcn_global_load_lds( \
    (const __attribute__((address_space(1))) unsigned int*)(const void*)(gp), \
    (__attribute__((address_space(3))) unsigned int*)(void*)(lp), 16, 0, 0)

// dims: B=2 T=2048 DM=1024 H=4 DK=256 DV=512; BT=4096
// Precision: GEMMs 3-term split-bf16. Retention: 1-term QK (q,k hi), 1-term PV
// (P,V single) — r11 measured dropping split terms here: absmax delta = 0.

// ---------------- split ALL inputs into bf16 hi/lo ----------------
__global__ __launch_bounds__(256) void cvt_split_k(
    const float* __restrict__ x,  const float* __restrict__ wq,
    const float* __restrict__ wk, const float* __restrict__ wv,
    const float* __restrict__ wg, const float* __restrict__ wo,
    u16* __restrict__ xh,  u16* __restrict__ xl,
    u16* __restrict__ wqh, u16* __restrict__ wql,
    u16* __restrict__ wkh, u16* __restrict__ wkl,
    u16* __restrict__ wvh, u16* __restrict__ wvl,
    u16* __restrict__ wgh, u16* __restrict__ wgl,
    u16* __restrict__ woh, u16* __restrict__ wol)
{
  long e = ((long)blockIdx.x * 256 + threadIdx.x) * 8;
  const float* src; u16 *dh, *dl;
  if (e < 4194304L)                    { src = x;  dh = xh;  dl = xl;  }
  else if ((e -= 4194304L) < 1048576L) { src = wq; dh = wqh; dl = wql; }
  else if ((e -= 1048576L) < 1048576L) { src = wk; dh = wkh; dl = wkl; }
  else if ((e -= 1048576L) < 2097152L) { src = wv; dh = wvh; dl = wvl; }
  else if ((e -= 2097152L) < 2097152L) { src = wg; dh = wgh; dl = wgl; }
  else                  { e -= 2097152L; src = wo; dh = woh; dl = wol; }
  f32x4 a = *(const f32x4*)(src + e);
  f32x4 b = *(const f32x4*)(src + e + 4);
  float f[8] = {a[0], a[1], a[2], a[3], b[0], b[1], b[2], b[3]};
  s16x8 rh, rl;
#pragma unroll
  for (int j = 0; j < 8; ++j) {
    u16 hi = f2bf(f[j]);
    rh[j] = (short)hi;
    rl[j] = (short)f2bf(f[j] - bf2f(hi));
  }
  *(s16x8*)(dh + e) = rh;
  *(s16x8*)(dl + e) = rl;
}

// ---------------- RoPE table: cos/sin [T=2048][128] ----------------
__global__ __launch_bounds__(256) void rope_table_k(float* __restrict__ ct, float* __restrict__ st)
{
  int i = blockIdx.x * 256 + threadIdx.x;     // 262144
  int t = i >> 7, j = i & 127;
  float freq = powf(10000.0f, -(float)j * (1.0f / 128.0f));
  float a = (float)t * freq;
  ct[i] = cosf(a);
  st[i] = sinf(a);
}

// ---------------- 3-term split GEMM core: C=(Ah+Al)(Bh+Bl), 128x128xBK32 -----
DEV void gemm3_core(const u16* __restrict__ Ah, const u16* __restrict__ Al,
                    const u16* __restrict__ Bh, const u16* __restrict__ Bl,
                    int K, int m0, u16* LAh, u16* LAl, u16* LBh, u16* LBl,
                    f32x4 acc[4][4], int tid)
{
  const int lane = tid & 63, wave = tid >> 6;
  const int wr = wave >> 1, wc = wave & 1;
  const int l15 = lane & 15, l4 = lane >> 4;
  const int nsteps = K >> 5;
  for (int kt = 0; kt < nsteps; ++kt) {
    const int kb = kt << 5;
#pragma unroll
    for (int c = 0; c < 2; ++c) {
      int chunk = c * 256 + tid;
      int row = chunk >> 2, kc = (chunk & 3) << 3;
      size_t aoff = (size_t)(m0 + row) * K + kb + kc;
      size_t boff = (size_t)row * K + kb + kc;
      char* ldst = (char*)0 + c * 4096 + wave * 1024;
      GL2LDS(Ah + aoff, (char*)LAh + (size_t)ldst);
      GL2LDS(Al + aoff, (char*)LAl + (size_t)ldst);
      GL2LDS(Bh + boff, (char*)LBh + (size_t)ldst);
      GL2LDS(Bl + boff, (char*)LBl + (size_t)ldst);
    }
    __syncthreads();
    s16x8 ah[4], al[4], bh[4], bl[4];
#pragma unroll
    for (int i = 0; i < 4; ++i) {
      int ar = (wr * 64 + i * 16 + l15) * 32 + l4 * 8;
      int br = (wc * 64 + i * 16 + l15) * 32 + l4 * 8;
      ah[i] = *(const s16x8*)&LAh[ar];
      al[i] = *(const s16x8*)&LAl[ar];
      bh[i] = *(const s16x8*)&LBh[br];
      bl[i] = *(const s16x8*)&LBl[br];
    }
#pragma unroll
    for (int i = 0; i < 4; ++i)
#pragma unroll
      for (int j = 0; j < 4; ++j) {
        acc[i][j] = __builtin_amdgcn_mfma_f32_16x16x32_bf16(ah[i], bh[j], acc[i][j], 0, 0, 0);
        acc[i][j] = __builtin_amdgcn_mfma_f32_16x16x32_bf16(ah[i], bl[j], acc[i][j], 0, 0, 0);
        acc[i][j] = __builtin_amdgcn_mfma_f32_16x16x32_bf16(al[i], bh[j], acc[i][j], 0, 0, 0);
      }
    __syncthreads();
  }
}

// ---------------- GEMM(q,k,v): x @ W^T, near-fp32; q,k fp32 out; v split -----
__global__ __launch_bounds__(256, 2) void gemm_qkv_k(
    const u16* __restrict__ xh, const u16* __restrict__ xl,
    const u16* __restrict__ wqh, const u16* __restrict__ wql,
    const u16* __restrict__ wkh, const u16* __restrict__ wkl,
    const u16* __restrict__ wvh, const u16* __restrict__ wvl,
    float* __restrict__ Qf, float* __restrict__ Kf,
    u16* __restrict__ vth, u16* __restrict__ vtl)
{
  __shared__ u16 LAh[4096], LAl[4096], LBh[4096], LBl[4096];
  const int m0 = blockIdx.x * 128;
  const int nt = blockIdx.y;
  const u16 *Bh, *Bl; int seg, nl0;
  if (nt < 8)       { Bh = wqh + (size_t)nt * 131072;        Bl = wql + (size_t)nt * 131072;        seg = 0; nl0 = nt * 128; }
  else if (nt < 16) { Bh = wkh + (size_t)(nt - 8) * 131072;  Bl = wkl + (size_t)(nt - 8) * 131072;  seg = 1; nl0 = (nt - 8) * 128; }
  else              { Bh = wvh + (size_t)(nt - 16) * 131072; Bl = wvl + (size_t)(nt - 16) * 131072; seg = 2; nl0 = (nt - 16) * 128; }

  f32x4 acc[4][4];
#pragma unroll
  for (int i = 0; i < 4; ++i)
#pragma unroll
    for (int j = 0; j < 4; ++j) acc[i][j] = (f32x4){0.f, 0.f, 0.f, 0.f};

  const int tid = threadIdx.x;
  gemm3_core(xh, xl, Bh, Bl, 1024, m0, LAh, LAl, LBh, LBl, acc, tid);

  const int lane = tid & 63, wave = tid >> 6;
  const int wr = wave >> 1, wc = wave & 1;
  const int l15 = lane & 15, l4 = lane >> 4;
#pragma unroll
  for (int i = 0; i < 4; ++i) {
    int rowb = m0 + wr * 64 + i * 16 + l4 * 4;
    int b_ = rowb >> 11, trow = rowb & 2047;
#pragma unroll
    for (int j = 0; j < 4; ++j) {
      int col = nl0 + wc * 64 + j * 16 + l15;
      f32x4 v = acc[i][j];
      if (seg <= 1) {          // q/k -> fp32 (b,h,t,d)
        int h_ = col >> 8, d_ = col & 255;
        float* dst = (seg == 0 ? Qf : Kf) + ((size_t)((b_ * 4 + h_) * 2048 + trow)) * 256 + d_;
#pragma unroll
        for (int r = 0; r < 4; ++r) dst[(size_t)r * 256] = v[r];
      } else {                 // v -> (b,h,d,t) split hi/lo bf16
        int h_ = col >> 9, d_ = col & 511;
        size_t base = ((size_t)((b_ * 4 + h_) * 512 + d_)) * 2048 + trow;
        s16x4 hv, lv;
#pragma unroll
        for (int r = 0; r < 4; ++r) {
          u16 hi = f2bf(v[r]);
          hv[r] = (short)hi;
          lv[r] = (short)f2bf(v[r] - bf2f(hi));
        }
        *(s16x4*)(vth + base) = hv;
        *(s16x4*)(vtl + base) = lv;
      }
    }
  }
}

// ---------------- GEMM(gate): silu(x @ Wg^T)*gw -> bf16 (bt, hdv) ------------
__global__ __launch_bounds__(256, 2) void gemm_gate_k(
    const u16* __restrict__ xh, const u16* __restrict__ xl,
    const u16* __restrict__ wgh, const u16* __restrict__ wgl,
    const float* __restrict__ gw, u16* __restrict__ gateb)
{
  __shared__ u16 LAh[4096], LAl[4096], LBh[4096], LBl[4096];
  const int m0 = blockIdx.x * 128;
  const int nl0 = blockIdx.y * 128;
  f32x4 acc[4][4];
#pragma unroll
  for (int i = 0; i < 4; ++i)
#pragma unroll
    for (int j = 0; j < 4; ++j) acc[i][j] = (f32x4){0.f, 0.f, 0.f, 0.f};
  const int tid = threadIdx.x;
  gemm3_core(xh, xl, wgh + (size_t)blockIdx.y * 131072, wgl + (size_t)blockIdx.y * 131072,
             1024, m0, LAh, LAl, LBh, LBl, acc, tid);
  const int lane = tid & 63, wave = tid >> 6;
  const int wr = wave >> 1, wc = wave & 1;
  const int l15 = lane & 15, l4 = lane >> 4;
#pragma unroll
  for (int i = 0; i < 4; ++i) {
    int rowb = m0 + wr * 64 + i * 16 + l4 * 4;
#pragma unroll
    for (int j = 0; j < 4; ++j) {
      int col = nl0 + wc * 64 + j * 16 + l15;
      float gwv = gw[col & 511];
#pragma unroll
      for (int r = 0; r < 4; ++r) {
        float g = acc[i][j][r];
        float gate = g / (1.0f + expf(-g)) * gwv;
        gateb[(size_t)(rowb + r) * 2048 + col] = f2bf(gate);
      }
    }
  }
}

// ---------------- RoPE fp32 -> in-place split bf16 [hi 256 | lo 256] ---------
// one wave per row; q rows scaled by dk^-0.5
__global__ __launch_bounds__(256) void rope_split_k(
    float* __restrict__ Qf, float* __restrict__ Kf,
    const float* __restrict__ ct, const float* __restrict__ st)
{
  int row = blockIdx.x * 4 + (threadIdx.x >> 6);   // 0..32767
  int lane = threadIdx.x & 63;
  float* base; float scale; int r = row;
  if (r < 16384) { base = Qf; scale = 0.0625f; }
  else { r -= 16384; base = Kf; scale = 1.0f; }
  int t = r & 2047;
  float* p = base + (size_t)r * 256;
  f32x4 v = *(const f32x4*)(p + lane * 4);
  int j0 = (lane & 31) * 4;
  f32x4 c = *(const f32x4*)(ct + t * 128 + j0);
  f32x4 s = *(const f32x4*)(st + t * 128 + j0);
  f32x4 sw, o;
#pragma unroll
  for (int q = 0; q < 4; ++q) sw[q] = __shfl_xor(v[q], 32);
#pragma unroll
  for (int q = 0; q < 4; ++q)
    o[q] = (lane < 32 ? v[q] * c[q] - sw[q] * s[q]
                      : sw[q] * s[q] + v[q] * c[q]) * scale;
  s16x4 hi4, lo4;
#pragma unroll
  for (int q = 0; q < 4; ++q) {
    u16 hi = f2bf(o[q]);
    hi4[q] = (short)hi;
    lo4[q] = (short)f2bf(o[q] - bf2f(hi));
  }
  u16* ub = (u16*)p;
  int dd = j0 + ((lane >> 5) << 7);
  *(s16x4*)(ub + dd) = hi4;          // hi plane [0,256)
  *(s16x4*)(ub + 256 + dd) = lo4;    // lo plane [256,512)
}

// ---------------- Retention + fused RMS-norm -> o_n bf16 ---------------------
// QBLK=32, 4 waves (sf,tf), 512 blocks, XCD affinity bh=bid&7, tail pairing.
// Latency-bound fixes (r11 counters: HBM 2%, Mfma 5.5%, 85% stall):
//  - K register prefetch (double-buffered, issued one full iter ahead)
//  - V loads issued at iter top, consumed after barrier (~600cy hiding)
//  - 1-term QK as 2 interleaved 4-deep MFMA chains (was 16-deep serial)
//  - P double-buffered in LDS -> ONE barrier per iter (was 2)
__global__ __launch_bounds__(256, 2) void retention_k(
    const u16* __restrict__ QS, const u16* __restrict__ KS,
    const u16* __restrict__ VTH, u16* __restrict__ ON)
{
  __shared__ u16 Plds0[32 * 32];
  __shared__ u16 Plds1[32 * 32];
  __shared__ float wpart[4][32];
  __shared__ float rmsl[32];

  const int bid = blockIdx.x;
  const int bh = bid & 7;          // XCD affinity under round-robin dispatch
  const int j = bid >> 3;          // 0..63
  const int qt = (j < 32) ? j : 95 - j;   // pair (j, j+32): iter sum = 65
  const int t0 = qt * 32;
  const int h = bh & 3;
  const float ld = log1pf(-exp2f(-5.0f - (float)h));
  const float c2 = ld * 1.44269504f;

  const int tid = threadIdx.x;
  const int lane = tid & 63, wave = tid >> 6;
  const int l15 = lane & 15, l4 = lane >> 4;
  const int sf = wave & 1, tf = wave >> 1;

  // Q fragments (hi only) for this wave's t-quadrant
  s16x8 qfh[8];
  {
    const u16* qrow = QS + (size_t)(bh * 2048 + t0 + tf * 16 + l15) * 512 + l4 * 8;
#pragma unroll
    for (int kf = 0; kf < 8; ++kf) qfh[kf] = *(const s16x8*)(qrow + kf * 32);
  }

  // per-lane base pointers (kt-invariant)
  const u16* kKrow = KS + ((size_t)(bh * 2048) + sf * 16 + l15) * 512 + l4 * 8;
  const u16* kVrow = VTH + ((size_t)(bh * 512 + wave * 128 + l15)) * 2048 + l4 * 8;

  // kt-invariant LDS offsets
  const int tl = tf * 16 + l15;
  const int tg = t0 + tl;
  const int pboff  = ((tl * 64 + (sf * 16 + l4 * 4) * 2) ^ ((tl & 7) << 4));
  const int pr0 = 0 * 16 + l15, pr1 = 1 * 16 + l15;
  const int ppoff0 = ((pr0 * 64 + l4 * 16) ^ ((pr0 & 7) << 4));
  const int ppoff1 = ((pr1 * 64 + l4 * 16) ^ ((pr1 & 7) << 4));

  f32x4 oacc[2][8];
#pragma unroll
  for (int i = 0; i < 2; ++i)
#pragma unroll
    for (int j2 = 0; j2 < 8; ++j2) oacc[i][j2] = (f32x4){0.f, 0.f, 0.f, 0.f};

#define LDK(KT, KR) do { const u16* kr_ = kKrow + (size_t)(KT) * 16384;      \
    _Pragma("unroll") for (int kf = 0; kf < 8; ++kf)                          \
      KR[kf] = *(const s16x8*)(kr_ + kf * 32); } while (0)

#define LDV(KT, VR) do { const u16* vr_ = kVrow + (KT) * 32;                  \
    _Pragma("unroll") for (int nf = 0; nf < 8; ++nf)                          \
      VR[nf] = *(const s16x8*)(vr_ + (size_t)nf * 32768); } while (0)

#define RET_BODY(KC, KN, PB)                                                  \
  do {                                                                        \
    const int s0 = kt * 32;                                                   \
    if (kt < qt) { LDK(kt + 1, KN); }                                         \
    LDV(kt, vcur);                                                            \
    f32x4 se = (f32x4){0.f, 0.f, 0.f, 0.f};                                   \
    f32x4 so = (f32x4){0.f, 0.f, 0.f, 0.f};                                   \
    _Pragma("unroll") for (int kf = 0; kf < 4; ++kf) {                        \
      se = __builtin_amdgcn_mfma_f32_16x16x32_bf16(KC[2*kf],   qfh[2*kf],   se, 0, 0, 0); \
      so = __builtin_amdgcn_mfma_f32_16x16x32_bf16(KC[2*kf+1], qfh[2*kf+1], so, 0, 0, 0); \
    }                                                                         \
    s16x4 pvh;                                                                \
    _Pragma("unroll") for (int r = 0; r < 4; ++r) {                           \
      int sl = sf * 16 + l4 * 4 + r;                                          \
      int diff = tg - (s0 + sl);                                              \
      float f = (diff >= 0) ? (se[r] + so[r]) * exp2f(c2 * (float)diff) : 0.0f; \
      pvh[r] = (short)f2bf(f);                                                \
    }                                                                         \
    *(s16x4*)((char*)PB + pboff) = pvh;                                       \
    __syncthreads();                                                          \
    s16x8 pah0 = *(const s16x8*)((char*)PB + ppoff0);                         \
    s16x8 pah1 = *(const s16x8*)((char*)PB + ppoff1);                         \
    _Pragma("unroll") for (int nf = 0; nf < 8; ++nf) {                        \
      oacc[0][nf] = __builtin_amdgcn_mfma_f32_16x16x32_bf16(pah0, vcur[nf], oacc[0][nf], 0, 0, 0); \
      oacc[1][nf] = __builtin_amdgcn_mfma_f32_16x16x32_bf16(pah1, vcur[nf], oacc[1][nf], 0, 0, 0); \
    }                                                                         \
  } while (0)

  s16x8 kA[8], kB[8], vcur[8];
  LDK(0, kA);
  int kt = 0;
  for (;;) {
    RET_BODY(kA, kB, Plds0);
    if (++kt > qt) break;
    RET_BODY(kB, kA, Plds1);
    if (++kt > qt) break;
  }
#undef RET_BODY
#undef LDV
#undef LDK

  // fused RMS over dv=512 per t-row, then o_n -> bf16
  float ss[2][4];
#pragma unroll
  for (int mf = 0; mf < 2; ++mf)
#pragma unroll
    for (int r = 0; r < 4; ++r) {
      float a = 0.f;
#pragma unroll
      for (int nf = 0; nf < 8; ++nf) { float o = oacc[mf][nf][r]; a += o * o; }
      ss[mf][r] = a;
    }
#pragma unroll
  for (int m = 1; m < 16; m <<= 1)
#pragma unroll
    for (int mf = 0; mf < 2; ++mf)
#pragma unroll
      for (int r = 0; r < 4; ++r) ss[mf][r] += __shfl_xor(ss[mf][r], m);
  if (l15 == 0) {
#pragma unroll
    for (int mf = 0; mf < 2; ++mf)
#pragma unroll
      for (int r = 0; r < 4; ++r) wpart[wave][mf * 16 + l4 * 4 + r] = ss[mf][r];
  }
  __syncthreads();
  if (tid < 32)
    rmsl[tid] = rsqrtf((wpart[0][tid] + wpart[1][tid] + wpart[2][tid] + wpart[3][tid])
                       * (1.0f / 512.0f) + 1e-5f);
  __syncthreads();
  u16* ob = ON + (size_t)(bh * 2048 + t0) * 512;
#pragma unroll
  for (int mf = 0; mf < 2; ++mf)
#pragma unroll
    for (int r = 0; r < 4; ++r) {
      int trow = mf * 16 + l4 * 4 + r;
      float rr = rmsl[trow];
#pragma unroll
      for (int nf = 0; nf < 8; ++nf)
        ob[(size_t)trow * 512 + wave * 128 + nf * 16 + l15] = f2bf(oacc[mf][nf][r] * rr);
    }
}

// ---------------- og = o_n * gate -> split hi/lo (bt, hdv) layout ------------
__global__ __launch_bounds__(256) void og_k(
    const u16* __restrict__ ON, const u16* __restrict__ gateb,
    u16* __restrict__ ogh, u16* __restrict__ ogl)
{
  size_t i = ((size_t)blockIdx.x * 256 + threadIdx.x) * 8;
  int d = (int)(i & 511);
  int t = (int)((i >> 9) & 2047);
  int bh = (int)(i >> 20);
  int h = bh & 3, b = bh >> 2;
  size_t gidx = ((size_t)(b * 2048 + t)) * 2048 + h * 512 + d;
  s16x8 o8 = *(const s16x8*)(ON + i);
  s16x8 g8 = *(const s16x8*)(gateb + gidx);
  s16x8 rh, rl;
#pragma unroll
  for (int j = 0; j < 8; ++j) {
    float p = bf2f((u16)o8[j]) * bf2f((u16)g8[j]);
    u16 hi = f2bf(p);
    rh[j] = (short)hi;
    rl[j] = (short)f2bf(p - bf2f(hi));
  }
  *(s16x8*)(ogh + gidx) = rh;
  *(s16x8*)(ogl + gidx) = rl;
}

// ---------------- GEMM2: (og_h+og_l) @ (Wo_h+Wo_l)^T -> out fp32 -------------
__global__ __launch_bounds__(256, 2) void gemm_out_k(
    const u16* __restrict__ OGh, const u16* __restrict__ OGl,
    const u16* __restrict__ WOh, const u16* __restrict__ WOl,
    float* __restrict__ OUT)
{
  __shared__ u16 LAh[4096], LAl[4096], LBh[4096], LBl[4096];
  const int m0 = blockIdx.x * 128;
  const int n0 = blockIdx.y * 128;
  f32x4 acc[4][4];
#pragma unroll
  for (int i = 0; i < 4; ++i)
#pragma unroll
    for (int j = 0; j < 4; ++j) acc[i][j] = (f32x4){0.f, 0.f, 0.f, 0.f};
  const int tid = threadIdx.x;
  gemm3_core(OGh, OGl, WOh + (size_t)n0 * 2048, WOl + (size_t)n0 * 2048,
             2048, m0, LAh, LAl, LBh, LBl, acc, tid);
  const int lane = tid & 63, wave = tid >> 6;
  const int wr = wave >> 1, wc = wave & 1;
  const int l15 = lane & 15, l4 = lane >> 4;
#pragma unroll
  for (int i = 0; i < 4; ++i) {
    int rowb = m0 + wr * 64 + i * 16 + l4 * 4;
#pragma unroll
    for (int j = 0; j < 4; ++j) {
      int col = n0 + wc * 64 + j * 16 + l15;
#pragma unroll
      for (int r = 0; r < 4; ++r)
        OUT[(size_t)(rowb + r) * 1024 + col] = acc[i][j][r];
    }
  }
}

// ---------------- launch ----------------
extern "C" void kernel_launch(void* const* d_in, const int* in_sizes, int n_in,
                              void* d_out, int out_size, void* d_ws, size_t ws_size,
                              hipStream_t stream)
{
  (void)in_sizes; (void)n_in; (void)out_size; (void)ws_size;
  const float* x  = (const float*)d_in[0];
  const float* wq = (const float*)d_in[1];
  const float* wk = (const float*)d_in[2];
  const float* wv = (const float*)d_in[3];
  const float* wg = (const float*)d_in[4];
  const float* wo = (const float*)d_in[5];
  const float* gw = (const float*)d_in[6];
  char* ws = (char*)d_ws;
#define MB(x) ((size_t)(x) * 1048576)
  // persistent regions (peak 112 MB)
  u16* xh  = (u16*)(ws + MB(0));    // dies after gemm_gate
  u16* xl  = (u16*)(ws + MB(8));
  u16* wqh = (u16*)(ws + MB(16));   // wq/wk/wv die after gemm_qkv
  u16* wql = (u16*)(ws + MB(18));
  u16* wkh = (u16*)(ws + MB(20));
  u16* wkl = (u16*)(ws + MB(22));
  u16* wvh = (u16*)(ws + MB(24));
  u16* wvl = (u16*)(ws + MB(28));
  u16* wgh = (u16*)(ws + MB(32));   // dies after gemm_gate
  u16* wgl = (u16*)(ws + MB(36));
  u16* woh = (u16*)(ws + MB(40));   // to end
  u16* wol = (u16*)(ws + MB(44));
  float* Qf = (float*)(ws + MB(48)); // fp32 -> split-in-place; dies after retention
  float* Kf = (float*)(ws + MB(64));
  u16* vth = (u16*)(ws + MB(80));   // dies after retention
  u16* vtl = (u16*)(ws + MB(96));
  // aliases over dead regions
  u16* gateb = (u16*)(ws + MB(16)); // over wq/wk/wv after gemm_qkv; dies after og_k
  float* ct  = (float*)(ws + MB(32)); // over wgh after gemm_gate; dies after rope
  float* st  = (float*)(ws + MB(33));
  u16* onb   = (u16*)(ws + MB(0));  // o_n over x after gemm_gate; dies after og_k
  u16* ogh   = (u16*)(ws + MB(48)); // over Qf/Kf after retention; to gemm_out
  u16* ogl   = (u16*)(ws + MB(64));
  u16* qs = (u16*)(ws + MB(48));    // split q/k views (in-place over Qf/Kf)
  u16* ks = (u16*)(ws + MB(64));
  float* out = (float*)d_out;

  cvt_split_k<<<6144, 256, 0, stream>>>(x, wq, wk, wv, wg, wo,
      xh, xl, wqh, wql, wkh, wkl, wvh, wvl, wgh, wgl, woh, wol);
  gemm_qkv_k<<<dim3(32, 32), 256, 0, stream>>>(xh, xl, wqh, wql, wkh, wkl, wvh, wvl,
      Qf, Kf, vth, vtl);
  gemm_gate_k<<<dim3(32, 16), 256, 0, stream>>>(xh, xl, wgh, wgl, gw, gateb);
  rope_table_k<<<1024, 256, 0, stream>>>(ct, st);
  rope_split_k<<<8192, 256, 0, stream>>>(Qf, Kf, ct, st);
  retention_k<<<512, 256, 0, stream>>>(qs, ks, vth, onb);
  og_k<<<4096, 256, 0, stream>>>(onb, gateb, ogh, ogl);
  gemm_out_k<<<dim3(32, 8), 256, 0, stream>>>(ogh, ogl, woh, wol, out);
#undef MB
}